// Round 18
// baseline (140.062 us; speedup 1.0000x reference)
//
#include <hip/hip_runtime.h>
#include <stdint.h>

typedef __attribute__((ext_vector_type(8))) short short8;
typedef __attribute__((ext_vector_type(4))) float floatx4;
typedef __attribute__((ext_vector_type(16))) float floatx16;

#define DEV static __device__ __forceinline__

DEV unsigned short f2bf(float f) {
  union { float f; uint32_t u; } v; v.f = f;
  return (unsigned short)((v.u + 0x7FFFu + ((v.u >> 16) & 1u)) >> 16);
}
DEV float bf2f(unsigned short h) {
  union { uint32_t u; float f; } v; v.u = ((uint32_t)h) << 16;
  return v.f;
}
DEV uint32_t cvtpk(float lo, float hi) {
  uint32_t d;
  asm("v_cvt_pk_bf16_f32 %0, %1, %2" : "=v"(d) : "v"(lo), "v"(hi));
  return d;
}
DEV void gload_lds16(const void* g, void* l) {
  __builtin_amdgcn_global_load_lds(
      (const __attribute__((address_space(1))) uint32_t*)g,
      (__attribute__((address_space(3))) uint32_t*)l, 16, 0, 0);
}

#if defined(__has_builtin)
#if __has_builtin(__builtin_amdgcn_permlane32_swap)
#define HAVE_PLSWAP 1
#endif
#endif
DEV void plswap(uint32_t& a, uint32_t& b) {
#ifdef HAVE_PLSWAP
  typedef unsigned int u2v __attribute__((ext_vector_type(2)));
  u2v r = __builtin_amdgcn_permlane32_swap(a, b, false, false);
  a = r.x; b = r.y;
#else
  uint32_t sa = (uint32_t)__shfl_xor((int)a, 32);
  uint32_t sb = (uint32_t)__shfl_xor((int)b, 32);
  uint32_t lane = __lane_id();
  uint32_t na = lane < 32 ? a : sb;
  uint32_t nb = lane < 32 ? sa : b;
  a = na; b = nb;
#endif
}
DEV float xmax32(float x) {
  union { float f; uint32_t u; } a, b; a.f = x; b.f = x;
  plswap(a.u, b.u);
  return fmaxf(a.f, b.f);
}
DEV float xsum32(float x) {
  union { float f; uint32_t u; } a, b; a.f = x; b.f = x;
  plswap(a.u, b.u);
  return a.f + b.f;
}

// ---------- fp32 -> bf16 convert: [X 4M][wq 1M][wk 1M][wv 1M][wo 1M] ----------
__global__ __launch_bounds__(256) void k_convert(
    const float* __restrict__ X, const float* __restrict__ Wq,
    const float* __restrict__ Wk, const float* __restrict__ Wv,
    const float* __restrict__ Wo, unsigned short* __restrict__ out) {
  long gid = (long)blockIdx.x * 256 + threadIdx.x;
  long e = gid * 8;
  int seg = (int)(e >> 20);
  const float* src; long base;
  if (seg < 4)      { src = X;  base = 0; }
  else if (seg == 4){ src = Wq; base = 4l << 20; }
  else if (seg == 5){ src = Wk; base = 5l << 20; }
  else if (seg == 6){ src = Wv; base = 6l << 20; }
  else              { src = Wo; base = 7l << 20; }
  const float4* s4 = (const float4*)(src + (e - base));
  float4 a = s4[0], b = s4[1];
  union { uint4 q; unsigned short s[8]; } u;
  u.s[0] = f2bf(a.x); u.s[1] = f2bf(a.y); u.s[2] = f2bf(a.z); u.s[3] = f2bf(a.w);
  u.s[4] = f2bf(b.x); u.s[5] = f2bf(b.y); u.s[6] = f2bf(b.z); u.s[7] = f2bf(b.w);
  *(uint4*)(out + e) = u.q;
}

// ---------- GEMM C = A * W^T   (A: MxK bf16 rm, W: NxK bf16 rm) ----------
// T2 swizzle per rule #21; K-loop start staggered per block.
// MODE 0: 128x128 tile; QKV fused epilogue. MODE 1: 64x128 tile, f32 out.
template <int MODE>
__global__ __launch_bounds__(256) void k_gemm(
    const unsigned short* __restrict__ A,
    const unsigned short* __restrict__ B0, const unsigned short* __restrict__ B1,
    const unsigned short* __restrict__ B2,
    unsigned short* __restrict__ Qo, unsigned short* __restrict__ Ko,
    unsigned short* __restrict__ VFo, float* __restrict__ Cf, int K) {
  constexpr int MI = (MODE == 1) ? 2 : 4;   // acc rows per wave (of 16)
  constexpr int BM = MI * 32;               // 64 or 128
  __shared__ unsigned short At[BM * 64];
  __shared__ unsigned short Bt[128 * 64];
  const int tid = threadIdx.x, lane = tid & 63, wid = tid >> 6;
  const int wm = (wid >> 1) * (MI * 16), wn = (wid & 1) * 64;
  const int g = lane >> 4, c0 = lane & 15;
  const int bm0 = blockIdx.x * BM;
  const int bnG = blockIdx.y * 128;
  const unsigned short* Bp;
  int bn0;
  if constexpr (MODE == 0) {
    int wsel = bnG >> 10;
    Bp = wsel == 0 ? B0 : (wsel == 1 ? B1 : B2);
    bn0 = bnG & 1023;
  } else { Bp = B0; bn0 = bnG; }
  floatx4 acc[MI][4] = {};
  const int nk = K >> 6;
  const int koff = (blockIdx.x + blockIdx.y * 3) & (nk - 1);
  const int swzr = (c0 & 7) << 4;
  for (int s = 0; s < nk; ++s) {
    const int kt = ((s + koff) & (nk - 1)) << 6;
#pragma unroll
    for (int i = 0; i < MI; ++i) {
      int o = tid * 16 + i * 4096;
      int row = o >> 7;
      int col = (o & 127) ^ ((row & 7) << 4);
      gload_lds16((const char*)A + ((long)(bm0 + row) * K + kt + (col >> 1)) * 2, (char*)At + o);
    }
#pragma unroll
    for (int i = 0; i < 4; ++i) {
      int o = tid * 16 + i * 4096;
      int row = o >> 7;
      int col = (o & 127) ^ ((row & 7) << 4);
      gload_lds16((const char*)Bp + ((long)(bn0 + row) * K + kt + (col >> 1)) * 2, (char*)Bt + o);
    }
    __syncthreads();
#pragma unroll
    for (int kk = 0; kk < 2; ++kk) {
      const int kb = kk * 64 + g * 16;
      short8 av[MI], bv[4];
#pragma unroll
      for (int mi = 0; mi < MI; ++mi)
        av[mi] = *(const short8*)((const char*)At + (wm + mi * 16 + c0) * 128 + (kb ^ swzr));
#pragma unroll
      for (int ni = 0; ni < 4; ++ni)
        bv[ni] = *(const short8*)((const char*)Bt + (wn + ni * 16 + c0) * 128 + (kb ^ swzr));
#pragma unroll
      for (int mi = 0; mi < MI; ++mi)
#pragma unroll
        for (int ni = 0; ni < 4; ++ni)
          acc[mi][ni] = __builtin_amdgcn_mfma_f32_16x16x32_bf16(av[mi], bv[ni], acc[mi][ni], 0, 0, 0);
    }
    __syncthreads();
  }
  if constexpr (MODE == 1) {
#pragma unroll
    for (int mi = 0; mi < MI; ++mi)
#pragma unroll
      for (int ni = 0; ni < 4; ++ni)
#pragma unroll
        for (int i = 0; i < 4; ++i) {
          int r = bm0 + wm + mi * 16 + 4 * g + i;
          int cg = bnG + wn + ni * 16 + c0;
          Cf[(long)r * 1024 + cg] = acc[mi][ni][i];
        }
  } else {
    const int wsel = bnG >> 10;  // block-uniform: 0=Q, 1=K, 2=V
#pragma unroll
    for (int mi = 0; mi < MI; ++mi)
#pragma unroll
      for (int ni = 0; ni < 4; ++ni)
#pragma unroll
        for (int i = 0; i < 4; ++i) {
          int r = bm0 + wm + mi * 16 + 4 * g + i;
          int cg = bnG + wn + ni * 16 + c0;
          int cc = cg & 1023, head = cc >> 6, dkk = cc & 63;
          int bb = r >> 11, ll = r & 2047;
          long bh = bb * 16 + head;
          float v = acc[mi][ni][i];
          if (wsel == 2) {
            int T = ll >> 6, rt = ll & 63;
            int m = rt >> 4, hb = (rt >> 3) & 1, j = rt & 7;
            int dvs = dkk >> 5, c = dkk & 31;
            VFo[bh * 131072 + T * 4096 + (dvs * 4 + m) * 512 + (hb * 32 + c) * 8 + j] = f2bf(v);
          } else {
            unsigned short* dst = wsel == 0 ? Qo : Ko;
            dst[(bh * 2048 + ll) * 64 + dkk] = f2bf(v);
          }
        }
  }
}

// ---------- fused: Q rope (blocks 0..511) + K rope+repack (blocks 512..1535) ----------
__global__ __launch_bounds__(256) void k_ropeQK(
    unsigned short* __restrict__ Qd, const unsigned short* __restrict__ Kin,
    unsigned short* __restrict__ KF, float qscale) {
  const int blk = blockIdx.x;
  const int tid = threadIdx.x;
  if (blk < 512) {
    int gid = blk * 256 + tid;             // (row, half)
    int row = gid >> 1, hf = gid & 1;
    int l = row & 2047;
    unsigned short* p = Qd + (long)row * 64 + hf * 32;
    union { uint4 q[4]; unsigned short s[32]; } u;
#pragma unroll
    for (int i = 0; i < 4; ++i) u.q[i] = ((const uint4*)p)[i];
    float lf = (float)l;
#pragma unroll
    for (int j = 0; j < 16; ++j) {
      int pp = hf * 16 + j;
      float ang = lf * exp2f(-(float)pp * 0.4152410118609203f);  // log2(10000)/32
      float sv, cv; sincosf(ang, &sv, &cv);
      float x1 = bf2f(u.s[2 * j]), x2 = bf2f(u.s[2 * j + 1]);
      u.s[2 * j]     = f2bf((x1 * cv - x2 * sv) * qscale);
      u.s[2 * j + 1] = f2bf((x1 * sv + x2 * cv) * qscale);
    }
#pragma unroll
    for (int i = 0; i < 4; ++i) ((uint4*)p)[i] = u.q[i];
  } else {
    const int kblk = blk - 512;            // 1024 = 32bh * 32T
    const int bh = kblk >> 5, T = kblk & 31;
    const unsigned short* src = Kin + ((long)bh * 2048 + T * 64) * 64;
    unsigned short* dst = KF + (long)kblk * 4096;
#pragma unroll
    for (int it = 0; it < 2; ++it) {
      int u = tid + it * 256;              // (kvs*4+dseg)*64 + lane
      int lane = u & 63, kd = u >> 6;
      int kvs = kd >> 2, dseg = kd & 3;
      int row = kvs * 32 + (lane & 31);
      int col = dseg * 16 + 8 * (lane >> 5);
      union { uint4 q; unsigned short s[8]; } v;
      v.q = *(const uint4*)(src + row * 64 + col);
      float lf = (float)(T * 64 + row);
#pragma unroll
      for (int j = 0; j < 4; ++j) {
        int p = (col >> 1) + j;            // rope pair index 0..31
        float ang = lf * exp2f(-(float)p * 0.4152410118609203f);
        float sv, cv; sincosf(ang, &sv, &cv);
        float x1 = bf2f(v.s[2 * j]), x2 = bf2f(v.s[2 * j + 1]);
        v.s[2 * j]     = f2bf(x1 * cv - x2 * sv);
        v.s[2 * j + 1] = f2bf(x1 * sv + x2 * cv);
      }
      *(uint4*)(dst + u * 8) = v.q;
    }
  }
}

// ---------- causal flash attention: 32x32 swapped MFMA, 2-way KV-split ----------
// 2 waves/block, same 32 q-rows; wave0 KV tiles [0,h0), wave1 [h0,nt).
// Lane (h=lane>>5, c=lane&31) owns q-row q0+c; KF/VF loads lane-contiguous.
// T5: setprio(1) around the MFMA clusters (QK, PV).
DEV void attn_tile(int T, int Tend, int ntm1, int qabs, int h, int c,
                   const unsigned short* __restrict__ kfbase,
                   const unsigned short* __restrict__ vfbase,
                   const short8 (&qf)[4],
                   const short8 (&kc0)[4], const short8 (&kc1)[4],
                   short8 (&kn0)[4], short8 (&kn1)[4],
                   floatx16& ctx0, floatx16& ctx1, float& m_, float& l_) {
  // prefetch K(T+1) into the other buffer (coalesced 1KB bursts)
  {
    const int Tn = T + 1 < Tend ? T + 1 : T;
    const unsigned short* kt = kfbase + (long)Tn * 4096;
#pragma unroll
    for (int d = 0; d < 4; ++d) kn0[d] = *(const short8*)(kt + d * 512);
#pragma unroll
    for (int d = 0; d < 4; ++d) kn1[d] = *(const short8*)(kt + 2048 + d * 512);
  }
  // V fragments for this tile (coalesced; consumed after softmax)
  const unsigned short* vt = vfbase + (long)T * 4096;
  short8 vf0[4], vf1[4];
#pragma unroll
  for (int m = 0; m < 4; ++m) vf0[m] = *(const short8*)(vt + m * 512);
#pragma unroll
  for (int m = 0; m < 4; ++m) vf1[m] = *(const short8*)(vt + 2048 + m * 512);

  // S^T tiles from current (already-resident) K fragments
  floatx16 s0 = {}, s1 = {};
  __builtin_amdgcn_s_setprio(1);
#pragma unroll
  for (int d = 0; d < 4; ++d) {
    s0 = __builtin_amdgcn_mfma_f32_32x32x16_bf16(kc0[d], qf[d], s0, 0, 0, 0);
    s1 = __builtin_amdgcn_mfma_f32_32x32x16_bf16(kc1[d], qf[d], s1, 0, 0, 0);
  }
  __builtin_amdgcn_s_setprio(0);

  // causal mask (uniform branch, final tile of the q-block only)
  if (T == ntm1) {
    const int kvb = T * 64 + 4 * h;
#pragma unroll
    for (int r = 0; r < 16; ++r) {
      const int off = (r & 3) + 8 * (r >> 2);
      if (kvb + off > qabs) s0[r] = -1e30f;
      if (kvb + 32 + off > qabs) s1[r] = -1e30f;
    }
  }
  // softmax: depth-5 in-lane trees + permlane cross-half
  float a4[8];
#pragma unroll
  for (int j = 0; j < 4; ++j) {
    a4[j]     = fmaxf(fmaxf(s0[4 * j], s0[4 * j + 1]), fmaxf(s0[4 * j + 2], s0[4 * j + 3]));
    a4[4 + j] = fmaxf(fmaxf(s1[4 * j], s1[4 * j + 1]), fmaxf(s1[4 * j + 2], s1[4 * j + 3]));
  }
  float mx = fmaxf(fmaxf(fmaxf(a4[0], a4[1]), fmaxf(a4[2], a4[3])),
                   fmaxf(fmaxf(a4[4], a4[5]), fmaxf(a4[6], a4[7])));
  mx = xmax32(mx);
  // defer-max (T13): only rescale when some row's max grew by > 8 (log2 domain)
  if (!__all(mx <= m_ + 8.0f)) {
    float mn = fmaxf(m_, mx);
    float sc = exp2f(m_ - mn);
    m_ = mn;
    l_ *= sc;
#pragma unroll
    for (int r = 0; r < 16; ++r) { ctx0[r] *= sc; ctx1[r] *= sc; }
  }
#pragma unroll
  for (int r = 0; r < 16; ++r) s0[r] = exp2f(s0[r] - m_);
#pragma unroll
  for (int r = 0; r < 16; ++r) s1[r] = exp2f(s1[r] - m_);
  float b4[8];
#pragma unroll
  for (int j = 0; j < 4; ++j) {
    b4[j]     = (s0[4 * j] + s0[4 * j + 1]) + (s0[4 * j + 2] + s0[4 * j + 3]);
    b4[4 + j] = (s1[4 * j] + s1[4 * j + 1]) + (s1[4 * j + 2] + s1[4 * j + 3]);
  }
  float rs = ((b4[0] + b4[1]) + (b4[2] + b4[3])) + ((b4[4] + b4[5]) + (b4[6] + b4[7]));
  rs = xsum32(rs);
  l_ += rs;

  // pack P to bf16 dwords
  uint32_t pd0[8], pd1[8];
#pragma unroll
  for (int d = 0; d < 8; ++d) {
    pd0[d] = cvtpk(s0[2 * d], s0[2 * d + 1]);
    pd1[d] = cvtpk(s1[2 * d], s1[2 * d + 1]);
  }
  // PV: B-frag pairs via single permlane32_swap each
  __builtin_amdgcn_s_setprio(1);
#pragma unroll
  for (int kvs = 0; kvs < 2; ++kvs) {
    const uint32_t* pd = kvs ? pd1 : pd0;
#pragma unroll
    for (int ks = 0; ks < 2; ++ks) {
      uint32_t u0 = pd[4 * ks], u2 = pd[4 * ks + 2];
      uint32_t u1 = pd[4 * ks + 1], u3 = pd[4 * ks + 3];
      plswap(u0, u2);
      plswap(u1, u3);
      union { uint32_t u[4]; short8 s; } bu;
      bu.u[0] = u0; bu.u[1] = u1; bu.u[2] = u2; bu.u[3] = u3;
      ctx0 = __builtin_amdgcn_mfma_f32_32x32x16_bf16(vf0[kvs * 2 + ks], bu.s, ctx0, 0, 0, 0);
      ctx1 = __builtin_amdgcn_mfma_f32_32x32x16_bf16(vf1[kvs * 2 + ks], bu.s, ctx1, 0, 0, 0);
    }
  }
  __builtin_amdgcn_s_setprio(0);
}

__global__ __launch_bounds__(128) void k_attn(
    const unsigned short* __restrict__ Q, const unsigned short* __restrict__ KF,
    const unsigned short* __restrict__ VF, unsigned short* __restrict__ O) {
  __shared__ float lctx[64][33];
  __shared__ float lml[64][2];
  const int bid = blockIdx.x;              // 2048 blocks = 8 XCD * 4 head * 64 a
  const int xcd = bid & 7, idx = bid >> 3;
  const int head = idx >> 6;               // 4 heads per XCD -> K/V L2-resident
  const int a = idx & 63;
  const int qs = (head < 2) ? a : 63 - a;  // CU-level balance under RR placement
  const int bh = xcd * 4 + head;
  const int tid = threadIdx.x;
  const int wid = tid >> 6, lane = tid & 63;
  const int h = lane >> 5, c = lane & 31;
  const unsigned short* Qh = Q + (long)bh * 2048 * 64;
  const unsigned short* kfbase = KF + (long)bh * 131072 + lane * 8;
  const unsigned short* vfbase = VF + (long)bh * 131072 + lane * 8;
  const int q0 = qs * 32, qabs = q0 + c;
  const int nt = (qs >> 1) + 1, ntm1 = nt - 1;
  const int h0 = nt >> 1;                  // wave0: [0,h0) (can be empty), wave1: [h0,nt)
  const int Tbeg = wid ? h0 : 0;
  const int Tend = wid ? nt : h0;

  // Q fragment (B-operand), hoisted: qf[dseg] = Q[q0+c][dseg*16+8h+j]
  short8 qf[4];
#pragma unroll
  for (int d = 0; d < 4; ++d)
    qf[d] = *(const short8*)(Qh + (long)(q0 + c) * 64 + d * 16 + 8 * h);

  floatx16 ctx0 = {}, ctx1 = {};  // ctx^T[dv][q] partials
  float m_ = -1e30f, l_ = 0.f;

  if (Tbeg < Tend) {
    // prologue: K(Tbeg) into buffer A (coalesced)
    short8 kA0[4], kA1[4], kB0[4], kB1[4];
    const unsigned short* kt0 = kfbase + (long)Tbeg * 4096;
#pragma unroll
    for (int d = 0; d < 4; ++d) kA0[d] = *(const short8*)(kt0 + d * 512);
#pragma unroll
    for (int d = 0; d < 4; ++d) kA1[d] = *(const short8*)(kt0 + 2048 + d * 512);
    int T = Tbeg;
    while (true) {
      attn_tile(T, Tend, ntm1, qabs, h, c, kfbase, vfbase, qf, kA0, kA1, kB0, kB1, ctx0, ctx1, m_, l_);
      if (++T >= Tend) break;
      attn_tile(T, Tend, ntm1, qabs, h, c, kfbase, vfbase, qf, kB0, kB1, kA0, kA1, ctx0, ctx1, m_, l_);
      if (++T >= Tend) break;
    }
  }
  // combine the two waves' partials through LDS
  if (wid) {
#pragma unroll
    for (int r = 0; r < 16; ++r) {
      lctx[lane][r] = ctx0[r];
      lctx[lane][16 + r] = ctx1[r];
    }
    lml[lane][0] = m_;
    lml[lane][1] = l_;
  }
  __syncthreads();
  if (!wid) {
    float m1 = lml[lane][0], l1 = lml[lane][1];
    float m = fmaxf(m_, m1);
    float e0 = exp2f(m_ - m), e1 = exp2f(m1 - m);
    float inv = 1.f / (l_ * e0 + l1 * e1);
    const int b = bh >> 4, hd = bh & 15;
    unsigned short* orow = O + (long)(b * 2048 + q0 + c) * 1024 + hd * 64;
#pragma unroll
    for (int m4 = 0; m4 < 4; ++m4) {
      uint2 w0, w1;
      w0.x = cvtpk((ctx0[4 * m4]     * e0 + lctx[lane][4 * m4]     * e1) * inv,
                   (ctx0[4 * m4 + 1] * e0 + lctx[lane][4 * m4 + 1] * e1) * inv);
      w0.y = cvtpk((ctx0[4 * m4 + 2] * e0 + lctx[lane][4 * m4 + 2] * e1) * inv,
                   (ctx0[4 * m4 + 3] * e0 + lctx[lane][4 * m4 + 3] * e1) * inv);
      *(uint2*)(orow + 8 * m4 + 4 * h) = w0;
      w1.x = cvtpk((ctx1[4 * m4]     * e0 + lctx[lane][16 + 4 * m4]     * e1) * inv,
                   (ctx1[4 * m4 + 1] * e0 + lctx[lane][16 + 4 * m4 + 1] * e1) * inv);
      w1.y = cvtpk((ctx1[4 * m4 + 2] * e0 + lctx[lane][16 + 4 * m4 + 2] * e1) * inv,
                   (ctx1[4 * m4 + 3] * e0 + lctx[lane][16 + 4 * m4 + 3] * e1) * inv);
      *(uint2*)(orow + 32 + 8 * m4 + 4 * h) = w1;
    }
  }
}

extern "C" void kernel_launch(void* const* d_in, const int* in_sizes, int n_in,
                              void* d_out, int out_size, void* d_ws, size_t ws_size,
                              hipStream_t stream) {
  const float* X  = (const float*)d_in[0];
  const float* Wq = (const float*)d_in[1];
  const float* Wk = (const float*)d_in[2];
  const float* Wv = (const float*)d_in[3];
  const float* Wo = (const float*)d_in[4];
  unsigned short* Xb  = (unsigned short*)d_ws;   // [0,4M) bf16 X (dead after gemm0)
  unsigned short* Wqb = Xb + (4l << 20);
  unsigned short* Wkb = Xb + (5l << 20);
  unsigned short* Wvb = Xb + (6l << 20);
  unsigned short* Wob = Xb + (7l << 20);
  unsigned short* Qw  = Xb + (8l << 20);         // Q rows [2,16,2048,64]
  unsigned short* Kw  = Xb + (12l << 20);        // K rows (dead after ropeQK)
  unsigned short* VFw = Xb + (16l << 20);        // fragment-major V (direct from gemm0)
  unsigned short* KFw = Xb;                      // fragment-major roped K (over dead X)
  unsigned short* Cw  = Xb + (20l << 20);        // ctx [b,l,1024]
  float* Out = (float*)d_out;

  k_convert<<<4096, 256, 0, stream>>>(X, Wq, Wk, Wv, Wo, Xb);
  k_gemm<0><<<dim3(32, 24), 256, 0, stream>>>(Xb, Wqb, Wkb, Wvb, Qw, Kw, VFw, nullptr, 1024);
  k_ropeQK<<<1536, 256, 0, stream>>>(Qw, Kw, KFw, 0.18033688011112042f);  // log2(e)/8
  k_attn<<<2048, 128, 0, stream>>>(Qw, KFw, VFw, Cw);
  k_gemm<1><<<dim3(64, 8), 256, 0, stream>>>(Cw, Wob, nullptr, nullptr,
                                             nullptr, nullptr, nullptr, Out, 1024);
}

// Round 19
// 134.333 us; speedup vs baseline: 1.0426x; 1.0426x over previous
//
#include <hip/hip_runtime.h>
#include <stdint.h>

typedef __attribute__((ext_vector_type(8))) short short8;
typedef __attribute__((ext_vector_type(4))) float floatx4;
typedef __attribute__((ext_vector_type(16))) float floatx16;

#define DEV static __device__ __forceinline__

DEV unsigned short f2bf(float f) {
  union { float f; uint32_t u; } v; v.f = f;
  return (unsigned short)((v.u + 0x7FFFu + ((v.u >> 16) & 1u)) >> 16);
}
DEV float bf2f(unsigned short h) {
  union { uint32_t u; float f; } v; v.u = ((uint32_t)h) << 16;
  return v.f;
}
DEV uint32_t cvtpk(float lo, float hi) {
  uint32_t d;
  asm("v_cvt_pk_bf16_f32 %0, %1, %2" : "=v"(d) : "v"(lo), "v"(hi));
  return d;
}
DEV void gload_lds16(const void* g, void* l) {
  __builtin_amdgcn_global_load_lds(
      (const __attribute__((address_space(1))) uint32_t*)g,
      (__attribute__((address_space(3))) uint32_t*)l, 16, 0, 0);
}

#if defined(__has_builtin)
#if __has_builtin(__builtin_amdgcn_permlane32_swap)
#define HAVE_PLSWAP 1
#endif
#endif
DEV void plswap(uint32_t& a, uint32_t& b) {
#ifdef HAVE_PLSWAP
  typedef unsigned int u2v __attribute__((ext_vector_type(2)));
  u2v r = __builtin_amdgcn_permlane32_swap(a, b, false, false);
  a = r.x; b = r.y;
#else
  uint32_t sa = (uint32_t)__shfl_xor((int)a, 32);
  uint32_t sb = (uint32_t)__shfl_xor((int)b, 32);
  uint32_t lane = __lane_id();
  uint32_t na = lane < 32 ? a : sb;
  uint32_t nb = lane < 32 ? sa : b;
  a = na; b = nb;
#endif
}
DEV float xmax32(float x) {
  union { float f; uint32_t u; } a, b; a.f = x; b.f = x;
  plswap(a.u, b.u);
  return fmaxf(a.f, b.f);
}
DEV float xsum32(float x) {
  union { float f; uint32_t u; } a, b; a.f = x; b.f = x;
  plswap(a.u, b.u);
  return a.f + b.f;
}

// ---------- fp32 -> bf16 convert: [X 4M][wq 1M][wk 1M][wv 1M][wo 1M] ----------
__global__ __launch_bounds__(256) void k_convert(
    const float* __restrict__ X, const float* __restrict__ Wq,
    const float* __restrict__ Wk, const float* __restrict__ Wv,
    const float* __restrict__ Wo, unsigned short* __restrict__ out) {
  long gid = (long)blockIdx.x * 256 + threadIdx.x;
  long e = gid * 8;
  int seg = (int)(e >> 20);
  const float* src; long base;
  if (seg < 4)      { src = X;  base = 0; }
  else if (seg == 4){ src = Wq; base = 4l << 20; }
  else if (seg == 5){ src = Wk; base = 5l << 20; }
  else if (seg == 6){ src = Wv; base = 6l << 20; }
  else              { src = Wo; base = 7l << 20; }
  const float4* s4 = (const float4*)(src + (e - base));
  float4 a = s4[0], b = s4[1];
  union { uint4 q; unsigned short s[8]; } u;
  u.s[0] = f2bf(a.x); u.s[1] = f2bf(a.y); u.s[2] = f2bf(a.z); u.s[3] = f2bf(a.w);
  u.s[4] = f2bf(b.x); u.s[5] = f2bf(b.y); u.s[6] = f2bf(b.z); u.s[7] = f2bf(b.w);
  *(uint4*)(out + e) = u.q;
}

// ---------- GEMM C = A * W^T   (A: MxK bf16 rm, W: NxK bf16 rm) ----------
// T2 swizzle per rule #21; K-loop start staggered; T1 XCD-chunked block swizzle.
// MODE 0: 128x128 tile; QKV fused epilogue. MODE 1: 64x128 tile, f32 out.
template <int MODE>
__global__ __launch_bounds__(256) void k_gemm(
    const unsigned short* __restrict__ A,
    const unsigned short* __restrict__ B0, const unsigned short* __restrict__ B1,
    const unsigned short* __restrict__ B2,
    unsigned short* __restrict__ Qo, unsigned short* __restrict__ Ko,
    unsigned short* __restrict__ VFo, float* __restrict__ Cf, int K) {
  constexpr int MI = (MODE == 1) ? 2 : 4;   // acc rows per wave (of 16)
  constexpr int BM = MI * 32;               // 64 or 128
  __shared__ unsigned short At[BM * 64];
  __shared__ unsigned short Bt[128 * 64];
  const int tid = threadIdx.x, lane = tid & 63, wid = tid >> 6;
  const int wm = (wid >> 1) * (MI * 16), wn = (wid & 1) * 64;
  const int g = lane >> 4, c0 = lane & 15;
  // T1: bijective XCD-chunked remap (nwg % 8 == 0 for both grids)
  const int nwg = gridDim.x * gridDim.y;
  const int bidl = blockIdx.y * gridDim.x + blockIdx.x;
  const int nb = (bidl & 7) * (nwg >> 3) + (bidl >> 3);
  const int bx = nb % gridDim.x, by = nb / gridDim.x;
  const int bm0 = bx * BM;
  const int bnG = by * 128;
  const unsigned short* Bp;
  int bn0;
  if constexpr (MODE == 0) {
    int wsel = bnG >> 10;
    Bp = wsel == 0 ? B0 : (wsel == 1 ? B1 : B2);
    bn0 = bnG & 1023;
  } else { Bp = B0; bn0 = bnG; }
  floatx4 acc[MI][4] = {};
  const int nk = K >> 6;
  const int koff = (bx + by * 3) & (nk - 1);
  const int swzr = (c0 & 7) << 4;
  for (int s = 0; s < nk; ++s) {
    const int kt = ((s + koff) & (nk - 1)) << 6;
#pragma unroll
    for (int i = 0; i < MI; ++i) {
      int o = tid * 16 + i * 4096;
      int row = o >> 7;
      int col = (o & 127) ^ ((row & 7) << 4);
      gload_lds16((const char*)A + ((long)(bm0 + row) * K + kt + (col >> 1)) * 2, (char*)At + o);
    }
#pragma unroll
    for (int i = 0; i < 4; ++i) {
      int o = tid * 16 + i * 4096;
      int row = o >> 7;
      int col = (o & 127) ^ ((row & 7) << 4);
      gload_lds16((const char*)Bp + ((long)(bn0 + row) * K + kt + (col >> 1)) * 2, (char*)Bt + o);
    }
    __syncthreads();
#pragma unroll
    for (int kk = 0; kk < 2; ++kk) {
      const int kb = kk * 64 + g * 16;
      short8 av[MI], bv[4];
#pragma unroll
      for (int mi = 0; mi < MI; ++mi)
        av[mi] = *(const short8*)((const char*)At + (wm + mi * 16 + c0) * 128 + (kb ^ swzr));
#pragma unroll
      for (int ni = 0; ni < 4; ++ni)
        bv[ni] = *(const short8*)((const char*)Bt + (wn + ni * 16 + c0) * 128 + (kb ^ swzr));
#pragma unroll
      for (int mi = 0; mi < MI; ++mi)
#pragma unroll
        for (int ni = 0; ni < 4; ++ni)
          acc[mi][ni] = __builtin_amdgcn_mfma_f32_16x16x32_bf16(av[mi], bv[ni], acc[mi][ni], 0, 0, 0);
    }
    __syncthreads();
  }
  if constexpr (MODE == 1) {
#pragma unroll
    for (int mi = 0; mi < MI; ++mi)
#pragma unroll
      for (int ni = 0; ni < 4; ++ni)
#pragma unroll
        for (int i = 0; i < 4; ++i) {
          int r = bm0 + wm + mi * 16 + 4 * g + i;
          int cg = bnG + wn + ni * 16 + c0;
          Cf[(long)r * 1024 + cg] = acc[mi][ni][i];
        }
  } else {
    const int wsel = bnG >> 10;  // block-uniform: 0=Q, 1=K, 2=V
#pragma unroll
    for (int mi = 0; mi < MI; ++mi)
#pragma unroll
      for (int ni = 0; ni < 4; ++ni)
#pragma unroll
        for (int i = 0; i < 4; ++i) {
          int r = bm0 + wm + mi * 16 + 4 * g + i;
          int cg = bnG + wn + ni * 16 + c0;
          int cc = cg & 1023, head = cc >> 6, dkk = cc & 63;
          int bb = r >> 11, ll = r & 2047;
          long bh = bb * 16 + head;
          float v = acc[mi][ni][i];
          if (wsel == 2) {
            int T = ll >> 6, rt = ll & 63;
            int m = rt >> 4, hb = (rt >> 3) & 1, j = rt & 7;
            int dvs = dkk >> 5, c = dkk & 31;
            VFo[bh * 131072 + T * 4096 + (dvs * 4 + m) * 512 + (hb * 32 + c) * 8 + j] = f2bf(v);
          } else {
            unsigned short* dst = wsel == 0 ? Qo : Ko;
            dst[(bh * 2048 + ll) * 64 + dkk] = f2bf(v);
          }
        }
  }
}

// ---------- fused: Q rope (blocks 0..511) + K rope+repack (blocks 512..1535) ----------
__global__ __launch_bounds__(256) void k_ropeQK(
    unsigned short* __restrict__ Qd, const unsigned short* __restrict__ Kin,
    unsigned short* __restrict__ KF, float qscale) {
  const int blk = blockIdx.x;
  const int tid = threadIdx.x;
  if (blk < 512) {
    int gid = blk * 256 + tid;             // (row, half)
    int row = gid >> 1, hf = gid & 1;
    int l = row & 2047;
    unsigned short* p = Qd + (long)row * 64 + hf * 32;
    union { uint4 q[4]; unsigned short s[32]; } u;
#pragma unroll
    for (int i = 0; i < 4; ++i) u.q[i] = ((const uint4*)p)[i];
    float lf = (float)l;
#pragma unroll
    for (int j = 0; j < 16; ++j) {
      int pp = hf * 16 + j;
      float ang = lf * exp2f(-(float)pp * 0.4152410118609203f);  // log2(10000)/32
      float sv, cv; sincosf(ang, &sv, &cv);
      float x1 = bf2f(u.s[2 * j]), x2 = bf2f(u.s[2 * j + 1]);
      u.s[2 * j]     = f2bf((x1 * cv - x2 * sv) * qscale);
      u.s[2 * j + 1] = f2bf((x1 * sv + x2 * cv) * qscale);
    }
#pragma unroll
    for (int i = 0; i < 4; ++i) ((uint4*)p)[i] = u.q[i];
  } else {
    const int kblk = blk - 512;            // 1024 = 32bh * 32T
    const int bh = kblk >> 5, T = kblk & 31;
    const unsigned short* src = Kin + ((long)bh * 2048 + T * 64) * 64;
    unsigned short* dst = KF + (long)kblk * 4096;
#pragma unroll
    for (int it = 0; it < 2; ++it) {
      int u = tid + it * 256;              // (kvs*4+dseg)*64 + lane
      int lane = u & 63, kd = u >> 6;
      int kvs = kd >> 2, dseg = kd & 3;
      int row = kvs * 32 + (lane & 31);
      int col = dseg * 16 + 8 * (lane >> 5);
      union { uint4 q; unsigned short s[8]; } v;
      v.q = *(const uint4*)(src + row * 64 + col);
      float lf = (float)(T * 64 + row);
#pragma unroll
      for (int j = 0; j < 4; ++j) {
        int p = (col >> 1) + j;            // rope pair index 0..31
        float ang = lf * exp2f(-(float)p * 0.4152410118609203f);
        float sv, cv; sincosf(ang, &sv, &cv);
        float x1 = bf2f(v.s[2 * j]), x2 = bf2f(v.s[2 * j + 1]);
        v.s[2 * j]     = f2bf(x1 * cv - x2 * sv);
        v.s[2 * j + 1] = f2bf(x1 * sv + x2 * cv);
      }
      *(uint4*)(dst + u * 8) = v.q;
    }
  }
}

// ---------- causal flash attention: 32x32 swapped MFMA, 2-way KV-split ----------
// 2 waves/block, same 32 q-rows; wave0 KV tiles [0,h0), wave1 [h0,nt).
// Lane (h=lane>>5, c=lane&31) owns q-row q0+c; KF/VF loads lane-contiguous.
DEV void attn_tile(int T, int Tend, int ntm1, int qabs, int h, int c,
                   const unsigned short* __restrict__ kfbase,
                   const unsigned short* __restrict__ vfbase,
                   const short8 (&qf)[4],
                   const short8 (&kc0)[4], const short8 (&kc1)[4],
                   short8 (&kn0)[4], short8 (&kn1)[4],
                   floatx16& ctx0, floatx16& ctx1, float& m_, float& l_) {
  // prefetch K(T+1) into the other buffer (coalesced 1KB bursts)
  {
    const int Tn = T + 1 < Tend ? T + 1 : T;
    const unsigned short* kt = kfbase + (long)Tn * 4096;
#pragma unroll
    for (int d = 0; d < 4; ++d) kn0[d] = *(const short8*)(kt + d * 512);
#pragma unroll
    for (int d = 0; d < 4; ++d) kn1[d] = *(const short8*)(kt + 2048 + d * 512);
  }
  // V fragments for this tile (coalesced; consumed after softmax)
  const unsigned short* vt = vfbase + (long)T * 4096;
  short8 vf0[4], vf1[4];
#pragma unroll
  for (int m = 0; m < 4; ++m) vf0[m] = *(const short8*)(vt + m * 512);
#pragma unroll
  for (int m = 0; m < 4; ++m) vf1[m] = *(const short8*)(vt + 2048 + m * 512);

  // S^T tiles from current (already-resident) K fragments
  floatx16 s0 = {}, s1 = {};
#pragma unroll
  for (int d = 0; d < 4; ++d)
    s0 = __builtin_amdgcn_mfma_f32_32x32x16_bf16(kc0[d], qf[d], s0, 0, 0, 0);
#pragma unroll
  for (int d = 0; d < 4; ++d)
    s1 = __builtin_amdgcn_mfma_f32_32x32x16_bf16(kc1[d], qf[d], s1, 0, 0, 0);

  // causal mask (uniform branch, final tile of the q-block only)
  if (T == ntm1) {
    const int kvb = T * 64 + 4 * h;
#pragma unroll
    for (int r = 0; r < 16; ++r) {
      const int off = (r & 3) + 8 * (r >> 2);
      if (kvb + off > qabs) s0[r] = -1e30f;
      if (kvb + 32 + off > qabs) s1[r] = -1e30f;
    }
  }
  // softmax: depth-5 in-lane trees + permlane cross-half
  float a4[8];
#pragma unroll
  for (int j = 0; j < 4; ++j) {
    a4[j]     = fmaxf(fmaxf(s0[4 * j], s0[4 * j + 1]), fmaxf(s0[4 * j + 2], s0[4 * j + 3]));
    a4[4 + j] = fmaxf(fmaxf(s1[4 * j], s1[4 * j + 1]), fmaxf(s1[4 * j + 2], s1[4 * j + 3]));
  }
  float mx = fmaxf(fmaxf(fmaxf(a4[0], a4[1]), fmaxf(a4[2], a4[3])),
                   fmaxf(fmaxf(a4[4], a4[5]), fmaxf(a4[6], a4[7])));
  mx = xmax32(mx);
  // defer-max (T13): only rescale when some row's max grew by > 8 (log2 domain)
  if (!__all(mx <= m_ + 8.0f)) {
    float mn = fmaxf(m_, mx);
    float sc = exp2f(m_ - mn);
    m_ = mn;
    l_ *= sc;
#pragma unroll
    for (int r = 0; r < 16; ++r) { ctx0[r] *= sc; ctx1[r] *= sc; }
  }
#pragma unroll
  for (int r = 0; r < 16; ++r) s0[r] = exp2f(s0[r] - m_);
#pragma unroll
  for (int r = 0; r < 16; ++r) s1[r] = exp2f(s1[r] - m_);
  float b4[8];
#pragma unroll
  for (int j = 0; j < 4; ++j) {
    b4[j]     = (s0[4 * j] + s0[4 * j + 1]) + (s0[4 * j + 2] + s0[4 * j + 3]);
    b4[4 + j] = (s1[4 * j] + s1[4 * j + 1]) + (s1[4 * j + 2] + s1[4 * j + 3]);
  }
  float rs = ((b4[0] + b4[1]) + (b4[2] + b4[3])) + ((b4[4] + b4[5]) + (b4[6] + b4[7]));
  rs = xsum32(rs);
  l_ += rs;

  // pack P to bf16 dwords
  uint32_t pd0[8], pd1[8];
#pragma unroll
  for (int d = 0; d < 8; ++d) {
    pd0[d] = cvtpk(s0[2 * d], s0[2 * d + 1]);
    pd1[d] = cvtpk(s1[2 * d], s1[2 * d + 1]);
  }
  // PV: B-frag pairs via single permlane32_swap each
#pragma unroll
  for (int kvs = 0; kvs < 2; ++kvs) {
    const uint32_t* pd = kvs ? pd1 : pd0;
#pragma unroll
    for (int ks = 0; ks < 2; ++ks) {
      uint32_t u0 = pd[4 * ks], u2 = pd[4 * ks + 2];
      uint32_t u1 = pd[4 * ks + 1], u3 = pd[4 * ks + 3];
      plswap(u0, u2);
      plswap(u1, u3);
      union { uint32_t u[4]; short8 s; } bu;
      bu.u[0] = u0; bu.u[1] = u1; bu.u[2] = u2; bu.u[3] = u3;
      ctx0 = __builtin_amdgcn_mfma_f32_32x32x16_bf16(vf0[kvs * 2 + ks], bu.s, ctx0, 0, 0, 0);
      ctx1 = __builtin_amdgcn_mfma_f32_32x32x16_bf16(vf1[kvs * 2 + ks], bu.s, ctx1, 0, 0, 0);
    }
  }
}

__global__ __launch_bounds__(128) void k_attn(
    const unsigned short* __restrict__ Q, const unsigned short* __restrict__ KF,
    const unsigned short* __restrict__ VF, unsigned short* __restrict__ O) {
  __shared__ float lctx[64][33];
  __shared__ float lml[64][2];
  const int bid = blockIdx.x;              // 2048 blocks = 8 XCD * 4 head * 64 a
  const int xcd = bid & 7, idx = bid >> 3;
  const int head = idx >> 6;               // 4 heads per XCD -> K/V L2-resident
  const int a = idx & 63;
  const int qs = (head < 2) ? a : 63 - a;  // CU-level balance under RR placement
  const int bh = xcd * 4 + head;
  const int tid = threadIdx.x;
  const int wid = tid >> 6, lane = tid & 63;
  const int h = lane >> 5, c = lane & 31;
  const unsigned short* Qh = Q + (long)bh * 2048 * 64;
  const unsigned short* kfbase = KF + (long)bh * 131072 + lane * 8;
  const unsigned short* vfbase = VF + (long)bh * 131072 + lane * 8;
  const int q0 = qs * 32, qabs = q0 + c;
  const int nt = (qs >> 1) + 1, ntm1 = nt - 1;
  const int h0 = nt >> 1;                  // wave0: [0,h0) (can be empty), wave1: [h0,nt)
  const int Tbeg = wid ? h0 : 0;
  const int Tend = wid ? nt : h0;

  // Q fragment (B-operand), hoisted: qf[dseg] = Q[q0+c][dseg*16+8h+j]
  short8 qf[4];
#pragma unroll
  for (int d = 0; d < 4; ++d)
    qf[d] = *(const short8*)(Qh + (long)(q0 + c) * 64 + d * 16 + 8 * h);

  floatx16 ctx0 = {}, ctx1 = {};  // ctx^T[dv][q] partials
  float m_ = -1e30f, l_ = 0.f;

  if (Tbeg < Tend) {
    // prologue: K(Tbeg) into buffer A (coalesced)
    short8 kA0[4], kA1[4], kB0[4], kB1[4];
    const unsigned short* kt0 = kfbase + (long)Tbeg * 4096;
#pragma unroll
    for (int d = 0; d < 4; ++d) kA0[d] = *(const short8*)(kt0 + d * 512);
#pragma unroll
    for (int d = 0; d < 4; ++d) kA1[d] = *(const short8*)(kt0 + 2048 + d * 512);
    int T = Tbeg;
    while (true) {
      attn_tile(T, Tend, ntm1, qabs, h, c, kfbase, vfbase, qf, kA0, kA1, kB0, kB1, ctx0, ctx1, m_, l_);
      if (++T >= Tend) break;
      attn_tile(T, Tend, ntm1, qabs, h, c, kfbase, vfbase, qf, kB0, kB1, kA0, kA1, ctx0, ctx1, m_, l_);
      if (++T >= Tend) break;
    }
  }
  // combine the two waves' partials through LDS
  if (wid) {
#pragma unroll
    for (int r = 0; r < 16; ++r) {
      lctx[lane][r] = ctx0[r];
      lctx[lane][16 + r] = ctx1[r];
    }
    lml[lane][0] = m_;
    lml[lane][1] = l_;
  }
  __syncthreads();
  if (!wid) {
    float m1 = lml[lane][0], l1 = lml[lane][1];
    float m = fmaxf(m_, m1);
    float e0 = exp2f(m_ - m), e1 = exp2f(m1 - m);
    float inv = 1.f / (l_ * e0 + l1 * e1);
    const int b = bh >> 4, hd = bh & 15;
    unsigned short* orow = O + (long)(b * 2048 + q0 + c) * 1024 + hd * 64;
#pragma unroll
    for (int m4 = 0; m4 < 4; ++m4) {
      uint2 w0, w1;
      w0.x = cvtpk((ctx0[4 * m4]     * e0 + lctx[lane][4 * m4]     * e1) * inv,
                   (ctx0[4 * m4 + 1] * e0 + lctx[lane][4 * m4 + 1] * e1) * inv);
      w0.y = cvtpk((ctx0[4 * m4 + 2] * e0 + lctx[lane][4 * m4 + 2] * e1) * inv,
                   (ctx0[4 * m4 + 3] * e0 + lctx[lane][4 * m4 + 3] * e1) * inv);
      *(uint2*)(orow + 8 * m4 + 4 * h) = w0;
      w1.x = cvtpk((ctx1[4 * m4]     * e0 + lctx[lane][16 + 4 * m4]     * e1) * inv,
                   (ctx1[4 * m4 + 1] * e0 + lctx[lane][16 + 4 * m4 + 1] * e1) * inv);
      w1.y = cvtpk((ctx1[4 * m4 + 2] * e0 + lctx[lane][16 + 4 * m4 + 2] * e1) * inv,
                   (ctx1[4 * m4 + 3] * e0 + lctx[lane][16 + 4 * m4 + 3] * e1) * inv);
      *(uint2*)(orow + 32 + 8 * m4 + 4 * h) = w1;
    }
  }
}

extern "C" void kernel_launch(void* const* d_in, const int* in_sizes, int n_in,
                              void* d_out, int out_size, void* d_ws, size_t ws_size,
                              hipStream_t stream) {
  const float* X  = (const float*)d_in[0];
  const float* Wq = (const float*)d_in[1];
  const float* Wk = (const float*)d_in[2];
  const float* Wv = (const float*)d_in[3];
  const float* Wo = (const float*)d_in[4];
  unsigned short* Xb  = (unsigned short*)d_ws;   // [0,4M) bf16 X (dead after gemm0)
  unsigned short* Wqb = Xb + (4l << 20);
  unsigned short* Wkb = Xb + (5l << 20);
  unsigned short* Wvb = Xb + (6l << 20);
  unsigned short* Wob = Xb + (7l << 20);
  unsigned short* Qw  = Xb + (8l << 20);         // Q rows [2,16,2048,64]
  unsigned short* Kw  = Xb + (12l << 20);        // K rows (dead after ropeQK)
  unsigned short* VFw = Xb + (16l << 20);        // fragment-major V (direct from gemm0)
  unsigned short* KFw = Xb;                      // fragment-major roped K (over dead X)
  unsigned short* Cw  = Xb + (20l << 20);        // ctx [b,l,1024]
  float* Out = (float*)d_out;

  k_convert<<<4096, 256, 0, stream>>>(X, Wq, Wk, Wv, Wo, Xb);
  k_gemm<0><<<dim3(32, 24), 256, 0, stream>>>(Xb, Wqb, Wkb, Wvb, Qw, Kw, VFw, nullptr, 1024);
  k_ropeQK<<<1536, 256, 0, stream>>>(Qw, Kw, KFw, 0.18033688011112042f);  // log2(e)/8
  k_attn<<<2048, 128, 0, stream>>>(Qw, KFw, VFw, Cw);
  k_gemm<1><<<dim3(64, 8), 256, 0, stream>>>(Cw, Wob, nullptr, nullptr,
                                             nullptr, nullptr, nullptr, Out, 1024);
}

// Round 20
// 127.846 us; speedup vs baseline: 1.0956x; 1.0507x over previous
//
#include <hip/hip_runtime.h>
#include <stdint.h>

typedef __attribute__((ext_vector_type(8))) short short8;
typedef __attribute__((ext_vector_type(4))) float floatx4;
typedef __attribute__((ext_vector_type(16))) float floatx16;

#define DEV static __device__ __forceinline__

DEV unsigned short f2bf(float f) {
  union { float f; uint32_t u; } v; v.f = f;
  return (unsigned short)((v.u + 0x7FFFu + ((v.u >> 16) & 1u)) >> 16);
}
DEV float bf2f(unsigned short h) {
  union { uint32_t u; float f; } v; v.u = ((uint32_t)h) << 16;
  return v.f;
}
DEV uint32_t cvtpk(float lo, float hi) {
  uint32_t d;
  asm("v_cvt_pk_bf16_f32 %0, %1, %2" : "=v"(d) : "v"(lo), "v"(hi));
  return d;
}
DEV void gload_lds16(const void* g, void* l) {
  __builtin_amdgcn_global_load_lds(
      (const __attribute__((address_space(1))) uint32_t*)g,
      (__attribute__((address_space(3))) uint32_t*)l, 16, 0, 0);
}

#if defined(__has_builtin)
#if __has_builtin(__builtin_amdgcn_permlane32_swap)
#define HAVE_PLSWAP 1
#endif
#endif
DEV void plswap(uint32_t& a, uint32_t& b) {
#ifdef HAVE_PLSWAP
  typedef unsigned int u2v __attribute__((ext_vector_type(2)));
  u2v r = __builtin_amdgcn_permlane32_swap(a, b, false, false);
  a = r.x; b = r.y;
#else
  uint32_t sa = (uint32_t)__shfl_xor((int)a, 32);
  uint32_t sb = (uint32_t)__shfl_xor((int)b, 32);
  uint32_t lane = __lane_id();
  uint32_t na = lane < 32 ? a : sb;
  uint32_t nb = lane < 32 ? sa : b;
  a = na; b = nb;
#endif
}
DEV float xmax32(float x) {
  union { float f; uint32_t u; } a, b; a.f = x; b.f = x;
  plswap(a.u, b.u);
  return fmaxf(a.f, b.f);
}
DEV float xsum32(float x) {
  union { float f; uint32_t u; } a, b; a.f = x; b.f = x;
  plswap(a.u, b.u);
  return a.f + b.f;
}

// ---------- fp32 -> bf16 convert: [X 4M][wq 1M][wk 1M][wv 1M][wo 1M] ----------
__global__ __launch_bounds__(256) void k_convert(
    const float* __restrict__ X, const float* __restrict__ Wq,
    const float* __restrict__ Wk, const float* __restrict__ Wv,
    const float* __restrict__ Wo, unsigned short* __restrict__ out) {
  long gid = (long)blockIdx.x * 256 + threadIdx.x;
  long e = gid * 8;
  int seg = (int)(e >> 20);
  const float* src; long base;
  if (seg < 4)      { src = X;  base = 0; }
  else if (seg == 4){ src = Wq; base = 4l << 20; }
  else if (seg == 5){ src = Wk; base = 5l << 20; }
  else if (seg == 6){ src = Wv; base = 6l << 20; }
  else              { src = Wo; base = 7l << 20; }
  const float4* s4 = (const float4*)(src + (e - base));
  float4 a = s4[0], b = s4[1];
  union { uint4 q; unsigned short s[8]; } u;
  u.s[0] = f2bf(a.x); u.s[1] = f2bf(a.y); u.s[2] = f2bf(a.z); u.s[3] = f2bf(a.w);
  u.s[4] = f2bf(b.x); u.s[5] = f2bf(b.y); u.s[6] = f2bf(b.z); u.s[7] = f2bf(b.w);
  *(uint4*)(out + e) = u.q;
}

// ---------- GEMM C = A * W^T   (A: MxK bf16 rm, W: NxK bf16 rm) ----------
// T2 swizzle per rule #21; K-loop start staggered per block.
// MODE 0: 128x128 tile; QKV fused epilogue. MODE 1: 64x128 tile, f32 out.
template <int MODE>
__global__ __launch_bounds__(256) void k_gemm(
    const unsigned short* __restrict__ A,
    const unsigned short* __restrict__ B0, const unsigned short* __restrict__ B1,
    const unsigned short* __restrict__ B2,
    unsigned short* __restrict__ Qo, unsigned short* __restrict__ Ko,
    unsigned short* __restrict__ VFo, float* __restrict__ Cf, int K) {
  constexpr int MI = (MODE == 1) ? 2 : 4;   // acc rows per wave (of 16)
  constexpr int BM = MI * 32;               // 64 or 128
  __shared__ unsigned short At[BM * 64];
  __shared__ unsigned short Bt[128 * 64];
  const int tid = threadIdx.x, lane = tid & 63, wid = tid >> 6;
  const int wm = (wid >> 1) * (MI * 16), wn = (wid & 1) * 64;
  const int g = lane >> 4, c0 = lane & 15;
  const int bm0 = blockIdx.x * BM;
  const int bnG = blockIdx.y * 128;
  const unsigned short* Bp;
  int bn0;
  if constexpr (MODE == 0) {
    int wsel = bnG >> 10;
    Bp = wsel == 0 ? B0 : (wsel == 1 ? B1 : B2);
    bn0 = bnG & 1023;
  } else { Bp = B0; bn0 = bnG; }
  floatx4 acc[MI][4] = {};
  const int nk = K >> 6;
  const int koff = (blockIdx.x + blockIdx.y * 3) & (nk - 1);
  const int swzr = (c0 & 7) << 4;
  for (int s = 0; s < nk; ++s) {
    const int kt = ((s + koff) & (nk - 1)) << 6;
#pragma unroll
    for (int i = 0; i < MI; ++i) {
      int o = tid * 16 + i * 4096;
      int row = o >> 7;
      int col = (o & 127) ^ ((row & 7) << 4);
      gload_lds16((const char*)A + ((long)(bm0 + row) * K + kt + (col >> 1)) * 2, (char*)At + o);
    }
#pragma unroll
    for (int i = 0; i < 4; ++i) {
      int o = tid * 16 + i * 4096;
      int row = o >> 7;
      int col = (o & 127) ^ ((row & 7) << 4);
      gload_lds16((const char*)Bp + ((long)(bn0 + row) * K + kt + (col >> 1)) * 2, (char*)Bt + o);
    }
    __syncthreads();
#pragma unroll
    for (int kk = 0; kk < 2; ++kk) {
      const int kb = kk * 64 + g * 16;
      short8 av[MI], bv[4];
#pragma unroll
      for (int mi = 0; mi < MI; ++mi)
        av[mi] = *(const short8*)((const char*)At + (wm + mi * 16 + c0) * 128 + (kb ^ swzr));
#pragma unroll
      for (int ni = 0; ni < 4; ++ni)
        bv[ni] = *(const short8*)((const char*)Bt + (wn + ni * 16 + c0) * 128 + (kb ^ swzr));
#pragma unroll
      for (int mi = 0; mi < MI; ++mi)
#pragma unroll
        for (int ni = 0; ni < 4; ++ni)
          acc[mi][ni] = __builtin_amdgcn_mfma_f32_16x16x32_bf16(av[mi], bv[ni], acc[mi][ni], 0, 0, 0);
    }
    __syncthreads();
  }
  if constexpr (MODE == 1) {
#pragma unroll
    for (int mi = 0; mi < MI; ++mi)
#pragma unroll
      for (int ni = 0; ni < 4; ++ni)
#pragma unroll
        for (int i = 0; i < 4; ++i) {
          int r = bm0 + wm + mi * 16 + 4 * g + i;
          int cg = bnG + wn + ni * 16 + c0;
          Cf[(long)r * 1024 + cg] = acc[mi][ni][i];
        }
  } else {
    const int wsel = bnG >> 10;  // block-uniform: 0=Q, 1=K, 2=V
#pragma unroll
    for (int mi = 0; mi < MI; ++mi)
#pragma unroll
      for (int ni = 0; ni < 4; ++ni)
#pragma unroll
        for (int i = 0; i < 4; ++i) {
          int r = bm0 + wm + mi * 16 + 4 * g + i;
          int cg = bnG + wn + ni * 16 + c0;
          int cc = cg & 1023, head = cc >> 6, dkk = cc & 63;
          int bb = r >> 11, ll = r & 2047;
          long bh = bb * 16 + head;
          float v = acc[mi][ni][i];
          if (wsel == 2) {
            int T = ll >> 6, rt = ll & 63;
            int m = rt >> 4, hb = (rt >> 3) & 1, j = rt & 7;
            int dvs = dkk >> 5, c = dkk & 31;
            VFo[bh * 131072 + T * 4096 + (dvs * 4 + m) * 512 + (hb * 32 + c) * 8 + j] = f2bf(v);
          } else {
            unsigned short* dst = wsel == 0 ? Qo : Ko;
            dst[(bh * 2048 + ll) * 64 + dkk] = f2bf(v);
          }
        }
  }
}

// ---------- fused: Q rope (blocks 0..511) + K rope+repack (blocks 512..1535) ----------
__global__ __launch_bounds__(256) void k_ropeQK(
    unsigned short* __restrict__ Qd, const unsigned short* __restrict__ Kin,
    unsigned short* __restrict__ KF, float qscale) {
  const int blk = blockIdx.x;
  const int tid = threadIdx.x;
  if (blk < 512) {
    int gid = blk * 256 + tid;             // (row, half)
    int row = gid >> 1, hf = gid & 1;
    int l = row & 2047;
    unsigned short* p = Qd + (long)row * 64 + hf * 32;
    union { uint4 q[4]; unsigned short s[32]; } u;
#pragma unroll
    for (int i = 0; i < 4; ++i) u.q[i] = ((const uint4*)p)[i];
    float lf = (float)l;
#pragma unroll
    for (int j = 0; j < 16; ++j) {
      int pp = hf * 16 + j;
      float ang = lf * exp2f(-(float)pp * 0.4152410118609203f);  // log2(10000)/32
      float sv, cv; sincosf(ang, &sv, &cv);
      float x1 = bf2f(u.s[2 * j]), x2 = bf2f(u.s[2 * j + 1]);
      u.s[2 * j]     = f2bf((x1 * cv - x2 * sv) * qscale);
      u.s[2 * j + 1] = f2bf((x1 * sv + x2 * cv) * qscale);
    }
#pragma unroll
    for (int i = 0; i < 4; ++i) ((uint4*)p)[i] = u.q[i];
  } else {
    const int kblk = blk - 512;            // 1024 = 32bh * 32T
    const int bh = kblk >> 5, T = kblk & 31;
    const unsigned short* src = Kin + ((long)bh * 2048 + T * 64) * 64;
    unsigned short* dst = KF + (long)kblk * 4096;
#pragma unroll
    for (int it = 0; it < 2; ++it) {
      int u = tid + it * 256;              // (kvs*4+dseg)*64 + lane
      int lane = u & 63, kd = u >> 6;
      int kvs = kd >> 2, dseg = kd & 3;
      int row = kvs * 32 + (lane & 31);
      int col = dseg * 16 + 8 * (lane >> 5);
      union { uint4 q; unsigned short s[8]; } v;
      v.q = *(const uint4*)(src + row * 64 + col);
      float lf = (float)(T * 64 + row);
#pragma unroll
      for (int j = 0; j < 4; ++j) {
        int p = (col >> 1) + j;            // rope pair index 0..31
        float ang = lf * exp2f(-(float)p * 0.4152410118609203f);
        float sv, cv; sincosf(ang, &sv, &cv);
        float x1 = bf2f(v.s[2 * j]), x2 = bf2f(v.s[2 * j + 1]);
        v.s[2 * j]     = f2bf(x1 * cv - x2 * sv);
        v.s[2 * j + 1] = f2bf(x1 * sv + x2 * cv);
      }
      *(uint4*)(dst + u * 8) = v.q;
    }
  }
}

// ---------- causal flash attention: 32x32 swapped MFMA, 2-way KV-split ----------
// 2 waves/block, same 32 q-rows; wave0 KV tiles [0,h0), wave1 [h0,nt).
// Lane (h=lane>>5, c=lane&31) owns q-row q0+c; KF/VF loads lane-contiguous.
DEV void attn_tile(int T, int Tend, int ntm1, int qabs, int h, int c,
                   const unsigned short* __restrict__ kfbase,
                   const unsigned short* __restrict__ vfbase,
                   const short8 (&qf)[4],
                   const short8 (&kc0)[4], const short8 (&kc1)[4],
                   short8 (&kn0)[4], short8 (&kn1)[4],
                   floatx16& ctx0, floatx16& ctx1, float& m_, float& l_) {
  // prefetch K(T+1) into the other buffer (coalesced 1KB bursts)
  {
    const int Tn = T + 1 < Tend ? T + 1 : T;
    const unsigned short* kt = kfbase + (long)Tn * 4096;
#pragma unroll
    for (int d = 0; d < 4; ++d) kn0[d] = *(const short8*)(kt + d * 512);
#pragma unroll
    for (int d = 0; d < 4; ++d) kn1[d] = *(const short8*)(kt + 2048 + d * 512);
  }
  // V fragments for this tile (coalesced; consumed after softmax)
  const unsigned short* vt = vfbase + (long)T * 4096;
  short8 vf0[4], vf1[4];
#pragma unroll
  for (int m = 0; m < 4; ++m) vf0[m] = *(const short8*)(vt + m * 512);
#pragma unroll
  for (int m = 0; m < 4; ++m) vf1[m] = *(const short8*)(vt + 2048 + m * 512);

  // S^T tiles from current (already-resident) K fragments
  floatx16 s0 = {}, s1 = {};
#pragma unroll
  for (int d = 0; d < 4; ++d)
    s0 = __builtin_amdgcn_mfma_f32_32x32x16_bf16(kc0[d], qf[d], s0, 0, 0, 0);
#pragma unroll
  for (int d = 0; d < 4; ++d)
    s1 = __builtin_amdgcn_mfma_f32_32x32x16_bf16(kc1[d], qf[d], s1, 0, 0, 0);

  // causal mask (uniform branch, final tile of the q-block only)
  if (T == ntm1) {
    const int kvb = T * 64 + 4 * h;
#pragma unroll
    for (int r = 0; r < 16; ++r) {
      const int off = (r & 3) + 8 * (r >> 2);
      if (kvb + off > qabs) s0[r] = -1e30f;
      if (kvb + 32 + off > qabs) s1[r] = -1e30f;
    }
  }
  // softmax: depth-5 in-lane trees + permlane cross-half
  float a4[8];
#pragma unroll
  for (int j = 0; j < 4; ++j) {
    a4[j]     = fmaxf(fmaxf(s0[4 * j], s0[4 * j + 1]), fmaxf(s0[4 * j + 2], s0[4 * j + 3]));
    a4[4 + j] = fmaxf(fmaxf(s1[4 * j], s1[4 * j + 1]), fmaxf(s1[4 * j + 2], s1[4 * j + 3]));
  }
  float mx = fmaxf(fmaxf(fmaxf(a4[0], a4[1]), fmaxf(a4[2], a4[3])),
                   fmaxf(fmaxf(a4[4], a4[5]), fmaxf(a4[6], a4[7])));
  mx = xmax32(mx);
  // defer-max (T13): only rescale when some row's max grew by > 8 (log2 domain)
  if (!__all(mx <= m_ + 8.0f)) {
    float mn = fmaxf(m_, mx);
    float sc = exp2f(m_ - mn);
    m_ = mn;
    l_ *= sc;
#pragma unroll
    for (int r = 0; r < 16; ++r) { ctx0[r] *= sc; ctx1[r] *= sc; }
  }
#pragma unroll
  for (int r = 0; r < 16; ++r) s0[r] = exp2f(s0[r] - m_);
#pragma unroll
  for (int r = 0; r < 16; ++r) s1[r] = exp2f(s1[r] - m_);
  float b4[8];
#pragma unroll
  for (int j = 0; j < 4; ++j) {
    b4[j]     = (s0[4 * j] + s0[4 * j + 1]) + (s0[4 * j + 2] + s0[4 * j + 3]);
    b4[4 + j] = (s1[4 * j] + s1[4 * j + 1]) + (s1[4 * j + 2] + s1[4 * j + 3]);
  }
  float rs = ((b4[0] + b4[1]) + (b4[2] + b4[3])) + ((b4[4] + b4[5]) + (b4[6] + b4[7]));
  rs = xsum32(rs);
  l_ += rs;

  // pack P to bf16 dwords
  uint32_t pd0[8], pd1[8];
#pragma unroll
  for (int d = 0; d < 8; ++d) {
    pd0[d] = cvtpk(s0[2 * d], s0[2 * d + 1]);
    pd1[d] = cvtpk(s1[2 * d], s1[2 * d + 1]);
  }
  // PV: B-frag pairs via single permlane32_swap each
#pragma unroll
  for (int kvs = 0; kvs < 2; ++kvs) {
    const uint32_t* pd = kvs ? pd1 : pd0;
#pragma unroll
    for (int ks = 0; ks < 2; ++ks) {
      uint32_t u0 = pd[4 * ks], u2 = pd[4 * ks + 2];
      uint32_t u1 = pd[4 * ks + 1], u3 = pd[4 * ks + 3];
      plswap(u0, u2);
      plswap(u1, u3);
      union { uint32_t u[4]; short8 s; } bu;
      bu.u[0] = u0; bu.u[1] = u1; bu.u[2] = u2; bu.u[3] = u3;
      ctx0 = __builtin_amdgcn_mfma_f32_32x32x16_bf16(vf0[kvs * 2 + ks], bu.s, ctx0, 0, 0, 0);
      ctx1 = __builtin_amdgcn_mfma_f32_32x32x16_bf16(vf1[kvs * 2 + ks], bu.s, ctx1, 0, 0, 0);
    }
  }
}

__global__ __launch_bounds__(128) void k_attn(
    const unsigned short* __restrict__ Q, const unsigned short* __restrict__ KF,
    const unsigned short* __restrict__ VF, unsigned short* __restrict__ O) {
  __shared__ float lctx[64][33];
  __shared__ float lml[64][2];
  const int bid = blockIdx.x;              // 2048 blocks = 8 XCD * 4 head * 64 a
  const int xcd = bid & 7, idx = bid >> 3;
  const int head = idx >> 6;               // 4 heads per XCD -> K/V L2-resident
  const int a = idx & 63;
  const int qs = (head < 2) ? a : 63 - a;  // CU-level balance under RR placement
  const int bh = xcd * 4 + head;
  const int tid = threadIdx.x;
  const int wid = tid >> 6, lane = tid & 63;
  const int h = lane >> 5, c = lane & 31;
  const unsigned short* Qh = Q + (long)bh * 2048 * 64;
  const unsigned short* kfbase = KF + (long)bh * 131072 + lane * 8;
  const unsigned short* vfbase = VF + (long)bh * 131072 + lane * 8;
  const int q0 = qs * 32, qabs = q0 + c;
  const int nt = (qs >> 1) + 1, ntm1 = nt - 1;
  const int h0 = nt >> 1;                  // wave0: [0,h0) (can be empty), wave1: [h0,nt)
  const int Tbeg = wid ? h0 : 0;
  const int Tend = wid ? nt : h0;

  // Q fragment (B-operand), hoisted: qf[dseg] = Q[q0+c][dseg*16+8h+j]
  short8 qf[4];
#pragma unroll
  for (int d = 0; d < 4; ++d)
    qf[d] = *(const short8*)(Qh + (long)(q0 + c) * 64 + d * 16 + 8 * h);

  floatx16 ctx0 = {}, ctx1 = {};  // ctx^T[dv][q] partials
  float m_ = -1e30f, l_ = 0.f;

  if (Tbeg < Tend) {
    // prologue: K(Tbeg) into buffer A (coalesced)
    short8 kA0[4], kA1[4], kB0[4], kB1[4];
    const unsigned short* kt0 = kfbase + (long)Tbeg * 4096;
#pragma unroll
    for (int d = 0; d < 4; ++d) kA0[d] = *(const short8*)(kt0 + d * 512);
#pragma unroll
    for (int d = 0; d < 4; ++d) kA1[d] = *(const short8*)(kt0 + 2048 + d * 512);
    int T = Tbeg;
    while (true) {
      attn_tile(T, Tend, ntm1, qabs, h, c, kfbase, vfbase, qf, kA0, kA1, kB0, kB1, ctx0, ctx1, m_, l_);
      if (++T >= Tend) break;
      attn_tile(T, Tend, ntm1, qabs, h, c, kfbase, vfbase, qf, kB0, kB1, kA0, kA1, ctx0, ctx1, m_, l_);
      if (++T >= Tend) break;
    }
  }
  // combine the two waves' partials through LDS
  if (wid) {
#pragma unroll
    for (int r = 0; r < 16; ++r) {
      lctx[lane][r] = ctx0[r];
      lctx[lane][16 + r] = ctx1[r];
    }
    lml[lane][0] = m_;
    lml[lane][1] = l_;
  }
  __syncthreads();
  if (!wid) {
    float m1 = lml[lane][0], l1 = lml[lane][1];
    float m = fmaxf(m_, m1);
    float e0 = exp2f(m_ - m), e1 = exp2f(m1 - m);
    float inv = 1.f / (l_ * e0 + l1 * e1);
    const int b = bh >> 4, hd = bh & 15;
    unsigned short* orow = O + (long)(b * 2048 + q0 + c) * 1024 + hd * 64;
#pragma unroll
    for (int m4 = 0; m4 < 4; ++m4) {
      uint2 w0, w1;
      w0.x = cvtpk((ctx0[4 * m4]     * e0 + lctx[lane][4 * m4]     * e1) * inv,
                   (ctx0[4 * m4 + 1] * e0 + lctx[lane][4 * m4 + 1] * e1) * inv);
      w0.y = cvtpk((ctx0[4 * m4 + 2] * e0 + lctx[lane][4 * m4 + 2] * e1) * inv,
                   (ctx0[4 * m4 + 3] * e0 + lctx[lane][4 * m4 + 3] * e1) * inv);
      *(uint2*)(orow + 8 * m4 + 4 * h) = w0;
      w1.x = cvtpk((ctx1[4 * m4]     * e0 + lctx[lane][16 + 4 * m4]     * e1) * inv,
                   (ctx1[4 * m4 + 1] * e0 + lctx[lane][16 + 4 * m4 + 1] * e1) * inv);
      w1.y = cvtpk((ctx1[4 * m4 + 2] * e0 + lctx[lane][16 + 4 * m4 + 2] * e1) * inv,
                   (ctx1[4 * m4 + 3] * e0 + lctx[lane][16 + 4 * m4 + 3] * e1) * inv);
      *(uint2*)(orow + 32 + 8 * m4 + 4 * h) = w1;
    }
  }
}

extern "C" void kernel_launch(void* const* d_in, const int* in_sizes, int n_in,
                              void* d_out, int out_size, void* d_ws, size_t ws_size,
                              hipStream_t stream) {
  const float* X  = (const float*)d_in[0];
  const float* Wq = (const float*)d_in[1];
  const float* Wk = (const float*)d_in[2];
  const float* Wv = (const float*)d_in[3];
  const float* Wo = (const float*)d_in[4];
  unsigned short* Xb  = (unsigned short*)d_ws;   // [0,4M) bf16 X (dead after gemm0)
  unsigned short* Wqb = Xb + (4l << 20);
  unsigned short* Wkb = Xb + (5l << 20);
  unsigned short* Wvb = Xb + (6l << 20);
  unsigned short* Wob = Xb + (7l << 20);
  unsigned short* Qw  = Xb + (8l << 20);         // Q rows [2,16,2048,64]
  unsigned short* Kw  = Xb + (12l << 20);        // K rows (dead after ropeQK)
  unsigned short* VFw = Xb + (16l << 20);        // fragment-major V (direct from gemm0)
  unsigned short* KFw = Xb;                      // fragment-major roped K (over dead X)
  unsigned short* Cw  = Xb + (20l << 20);        // ctx [b,l,1024]
  float* Out = (float*)d_out;

  k_convert<<<4096, 256, 0, stream>>>(X, Wq, Wk, Wv, Wo, Xb);
  k_gemm<0><<<dim3(32, 24), 256, 0, stream>>>(Xb, Wqb, Wkb, Wvb, Qw, Kw, VFw, nullptr, 1024);
  k_ropeQK<<<1536, 256, 0, stream>>>(Qw, Kw, KFw, 0.18033688011112042f);  // log2(e)/8
  k_attn<<<2048, 128, 0, stream>>>(Qw, KFw, VFw, Cw);
  k_gemm<1><<<dim3(64, 8), 256, 0, stream>>>(Cw, Wob, nullptr, nullptr,
                                             nullptr, nullptr, nullptr, Out, 1024);
}

// Round 21
// 127.645 us; speedup vs baseline: 1.0973x; 1.0016x over previous
//
#include <hip/hip_runtime.h>
#include <stdint.h>

typedef __attribute__((ext_vector_type(8))) short short8;
typedef __attribute__((ext_vector_type(4))) float floatx4;
typedef __attribute__((ext_vector_type(16))) float floatx16;

#define DEV static __device__ __forceinline__

DEV unsigned short f2bf(float f) {
  union { float f; uint32_t u; } v; v.f = f;
  return (unsigned short)((v.u + 0x7FFFu + ((v.u >> 16) & 1u)) >> 16);
}
DEV float bf2f(unsigned short h) {
  union { uint32_t u; float f; } v; v.u = ((uint32_t)h) << 16;
  return v.f;
}
DEV uint32_t cvtpk(float lo, float hi) {
  uint32_t d;
  asm("v_cvt_pk_bf16_f32 %0, %1, %2" : "=v"(d) : "v"(lo), "v"(hi));
  return d;
}
DEV void gload_lds16(const void* g, void* l) {
  __builtin_amdgcn_global_load_lds(
      (const __attribute__((address_space(1))) uint32_t*)g,
      (__attribute__((address_space(3))) uint32_t*)l, 16, 0, 0);
}

#if defined(__has_builtin)
#if __has_builtin(__builtin_amdgcn_permlane32_swap)
#define HAVE_PLSWAP 1
#endif
#endif
DEV void plswap(uint32_t& a, uint32_t& b) {
#ifdef HAVE_PLSWAP
  typedef unsigned int u2v __attribute__((ext_vector_type(2)));
  u2v r = __builtin_amdgcn_permlane32_swap(a, b, false, false);
  a = r.x; b = r.y;
#else
  uint32_t sa = (uint32_t)__shfl_xor((int)a, 32);
  uint32_t sb = (uint32_t)__shfl_xor((int)b, 32);
  uint32_t lane = __lane_id();
  uint32_t na = lane < 32 ? a : sb;
  uint32_t nb = lane < 32 ? sa : b;
  a = na; b = nb;
#endif
}
DEV float xmax32(float x) {
  union { float f; uint32_t u; } a, b; a.f = x; b.f = x;
  plswap(a.u, b.u);
  return fmaxf(a.f, b.f);
}
DEV float xsum32(float x) {
  union { float f; uint32_t u; } a, b; a.f = x; b.f = x;
  plswap(a.u, b.u);
  return a.f + b.f;
}

// ---------- fp32 -> bf16 convert: [X 4M][wq 1M][wk 1M][wv 1M][wo 1M] ----------
__global__ __launch_bounds__(256) void k_convert(
    const float* __restrict__ X, const float* __restrict__ Wq,
    const float* __restrict__ Wk, const float* __restrict__ Wv,
    const float* __restrict__ Wo, unsigned short* __restrict__ out) {
  long gid = (long)blockIdx.x * 256 + threadIdx.x;
  long e = gid * 8;
  int seg = (int)(e >> 20);
  const float* src; long base;
  if (seg < 4)      { src = X;  base = 0; }
  else if (seg == 4){ src = Wq; base = 4l << 20; }
  else if (seg == 5){ src = Wk; base = 5l << 20; }
  else if (seg == 6){ src = Wv; base = 6l << 20; }
  else              { src = Wo; base = 7l << 20; }
  const float4* s4 = (const float4*)(src + (e - base));
  float4 a = s4[0], b = s4[1];
  union { uint4 q; unsigned short s[8]; } u;
  u.s[0] = f2bf(a.x); u.s[1] = f2bf(a.y); u.s[2] = f2bf(a.z); u.s[3] = f2bf(a.w);
  u.s[4] = f2bf(b.x); u.s[5] = f2bf(b.y); u.s[6] = f2bf(b.z); u.s[7] = f2bf(b.w);
  *(uint4*)(out + e) = u.q;
}

// ---------- GEMM C = A * W^T   (A: MxK bf16 rm, W: NxK bf16 rm) ----------
// T2 swizzle per rule #21; K-loop start staggered per block.
// MODE 0: 128x128 tile; QKV fused epilogue. MODE 1: 64x128 tile, f32 out.
template <int MODE>
__global__ __launch_bounds__(256) void k_gemm(
    const unsigned short* __restrict__ A,
    const unsigned short* __restrict__ B0, const unsigned short* __restrict__ B1,
    const unsigned short* __restrict__ B2,
    unsigned short* __restrict__ Qo, unsigned short* __restrict__ Ko,
    unsigned short* __restrict__ VFo, float* __restrict__ Cf, int K) {
  constexpr int MI = (MODE == 1) ? 2 : 4;   // acc rows per wave (of 16)
  constexpr int BM = MI * 32;               // 64 or 128
  __shared__ unsigned short At[BM * 64];
  __shared__ unsigned short Bt[128 * 64];
  const int tid = threadIdx.x, lane = tid & 63, wid = tid >> 6;
  const int wm = (wid >> 1) * (MI * 16), wn = (wid & 1) * 64;
  const int g = lane >> 4, c0 = lane & 15;
  const int bm0 = blockIdx.x * BM;
  const int bnG = blockIdx.y * 128;
  const unsigned short* Bp;
  int bn0;
  if constexpr (MODE == 0) {
    int wsel = bnG >> 10;
    Bp = wsel == 0 ? B0 : (wsel == 1 ? B1 : B2);
    bn0 = bnG & 1023;
  } else { Bp = B0; bn0 = bnG; }
  floatx4 acc[MI][4] = {};
  const int nk = K >> 6;
  const int koff = (blockIdx.x + blockIdx.y * 3) & (nk - 1);
  const int swzr = (c0 & 7) << 4;
  for (int s = 0; s < nk; ++s) {
    const int kt = ((s + koff) & (nk - 1)) << 6;
#pragma unroll
    for (int i = 0; i < MI; ++i) {
      int o = tid * 16 + i * 4096;
      int row = o >> 7;
      int col = (o & 127) ^ ((row & 7) << 4);
      gload_lds16((const char*)A + ((long)(bm0 + row) * K + kt + (col >> 1)) * 2, (char*)At + o);
    }
#pragma unroll
    for (int i = 0; i < 4; ++i) {
      int o = tid * 16 + i * 4096;
      int row = o >> 7;
      int col = (o & 127) ^ ((row & 7) << 4);
      gload_lds16((const char*)Bp + ((long)(bn0 + row) * K + kt + (col >> 1)) * 2, (char*)Bt + o);
    }
    __syncthreads();
#pragma unroll
    for (int kk = 0; kk < 2; ++kk) {
      const int kb = kk * 64 + g * 16;
      short8 av[MI], bv[4];
#pragma unroll
      for (int mi = 0; mi < MI; ++mi)
        av[mi] = *(const short8*)((const char*)At + (wm + mi * 16 + c0) * 128 + (kb ^ swzr));
#pragma unroll
      for (int ni = 0; ni < 4; ++ni)
        bv[ni] = *(const short8*)((const char*)Bt + (wn + ni * 16 + c0) * 128 + (kb ^ swzr));
#pragma unroll
      for (int mi = 0; mi < MI; ++mi)
#pragma unroll
        for (int ni = 0; ni < 4; ++ni)
          acc[mi][ni] = __builtin_amdgcn_mfma_f32_16x16x32_bf16(av[mi], bv[ni], acc[mi][ni], 0, 0, 0);
    }
    __syncthreads();
  }
  if constexpr (MODE == 1) {
#pragma unroll
    for (int mi = 0; mi < MI; ++mi)
#pragma unroll
      for (int ni = 0; ni < 4; ++ni)
#pragma unroll
        for (int i = 0; i < 4; ++i) {
          int r = bm0 + wm + mi * 16 + 4 * g + i;
          int cg = bnG + wn + ni * 16 + c0;
          Cf[(long)r * 1024 + cg] = acc[mi][ni][i];
        }
  } else {
    const int wsel = bnG >> 10;  // block-uniform: 0=Q, 1=K, 2=V
#pragma unroll
    for (int mi = 0; mi < MI; ++mi)
#pragma unroll
      for (int ni = 0; ni < 4; ++ni)
#pragma unroll
        for (int i = 0; i < 4; ++i) {
          int r = bm0 + wm + mi * 16 + 4 * g + i;
          int cg = bnG + wn + ni * 16 + c0;
          int cc = cg & 1023, head = cc >> 6, dkk = cc & 63;
          int bb = r >> 11, ll = r & 2047;
          long bh = bb * 16 + head;
          float v = acc[mi][ni][i];
          if (wsel == 2) {
            int T = ll >> 6, rt = ll & 63;
            int m = rt >> 4, hb = (rt >> 3) & 1, j = rt & 7;
            int dvs = dkk >> 5, c = dkk & 31;
            VFo[bh * 131072 + T * 4096 + (dvs * 4 + m) * 512 + (hb * 32 + c) * 8 + j] = f2bf(v);
          } else {
            unsigned short* dst = wsel == 0 ? Qo : Ko;
            dst[(bh * 2048 + ll) * 64 + dkk] = f2bf(v);
          }
        }
  }
}

// ---------- K: rope + repack to fragment-major KF[bh][T][kvs][dseg][lane][8] ----------
__global__ __launch_bounds__(256) void k_ropeK(
    const unsigned short* __restrict__ Kin, unsigned short* __restrict__ KF) {
  const int kblk = blockIdx.x;           // 1024 = 32bh * 32T
  const int bh = kblk >> 5, T = kblk & 31;
  const int tid = threadIdx.x;
  const unsigned short* src = Kin + ((long)bh * 2048 + T * 64) * 64;
  unsigned short* dst = KF + (long)kblk * 4096;
#pragma unroll
  for (int it = 0; it < 2; ++it) {
    int u = tid + it * 256;              // (kvs*4+dseg)*64 + lane
    int lane = u & 63, kd = u >> 6;
    int kvs = kd >> 2, dseg = kd & 3;
    int row = kvs * 32 + (lane & 31);
    int col = dseg * 16 + 8 * (lane >> 5);
    union { uint4 q; unsigned short s[8]; } v;
    v.q = *(const uint4*)(src + row * 64 + col);
    float lf = (float)(T * 64 + row);
#pragma unroll
    for (int j = 0; j < 4; ++j) {
      int p = (col >> 1) + j;            // rope pair index 0..31
      float ang = lf * exp2f(-(float)p * 0.4152410118609203f);
      float sv, cv; sincosf(ang, &sv, &cv);
      float x1 = bf2f(v.s[2 * j]), x2 = bf2f(v.s[2 * j + 1]);
      v.s[2 * j]     = f2bf(x1 * cv - x2 * sv);
      v.s[2 * j + 1] = f2bf(x1 * sv + x2 * cv);
    }
    *(uint4*)(dst + u * 8) = v.q;
  }
}

// ---------- causal flash attention: 32x32 swapped MFMA, 2-way KV-split ----------
// 2 waves/block, same 32 q-rows; wave0 KV tiles [0,h0), wave1 [h0,nt).
// Lane (h=lane>>5, c=lane&31) owns q-row q0+c; KF/VF loads lane-contiguous.
// Q-rope folded into the fragment load (pairs adjacent in-lane; once/block).
DEV void attn_tile(int T, int Tend, int ntm1, int qabs, int h, int c,
                   const unsigned short* __restrict__ kfbase,
                   const unsigned short* __restrict__ vfbase,
                   const short8 (&qf)[4],
                   const short8 (&kc0)[4], const short8 (&kc1)[4],
                   short8 (&kn0)[4], short8 (&kn1)[4],
                   floatx16& ctx0, floatx16& ctx1, float& m_, float& l_) {
  // prefetch K(T+1) into the other buffer (coalesced 1KB bursts)
  {
    const int Tn = T + 1 < Tend ? T + 1 : T;
    const unsigned short* kt = kfbase + (long)Tn * 4096;
#pragma unroll
    for (int d = 0; d < 4; ++d) kn0[d] = *(const short8*)(kt + d * 512);
#pragma unroll
    for (int d = 0; d < 4; ++d) kn1[d] = *(const short8*)(kt + 2048 + d * 512);
  }
  // V fragments for this tile (coalesced; consumed after softmax)
  const unsigned short* vt = vfbase + (long)T * 4096;
  short8 vf0[4], vf1[4];
#pragma unroll
  for (int m = 0; m < 4; ++m) vf0[m] = *(const short8*)(vt + m * 512);
#pragma unroll
  for (int m = 0; m < 4; ++m) vf1[m] = *(const short8*)(vt + 2048 + m * 512);

  // S^T tiles from current (already-resident) K fragments
  floatx16 s0 = {}, s1 = {};
#pragma unroll
  for (int d = 0; d < 4; ++d)
    s0 = __builtin_amdgcn_mfma_f32_32x32x16_bf16(kc0[d], qf[d], s0, 0, 0, 0);
#pragma unroll
  for (int d = 0; d < 4; ++d)
    s1 = __builtin_amdgcn_mfma_f32_32x32x16_bf16(kc1[d], qf[d], s1, 0, 0, 0);

  // causal mask (uniform branch, final tile of the q-block only)
  if (T == ntm1) {
    const int kvb = T * 64 + 4 * h;
#pragma unroll
    for (int r = 0; r < 16; ++r) {
      const int off = (r & 3) + 8 * (r >> 2);
      if (kvb + off > qabs) s0[r] = -1e30f;
      if (kvb + 32 + off > qabs) s1[r] = -1e30f;
    }
  }
  // softmax: depth-5 in-lane trees + permlane cross-half
  float a4[8];
#pragma unroll
  for (int j = 0; j < 4; ++j) {
    a4[j]     = fmaxf(fmaxf(s0[4 * j], s0[4 * j + 1]), fmaxf(s0[4 * j + 2], s0[4 * j + 3]));
    a4[4 + j] = fmaxf(fmaxf(s1[4 * j], s1[4 * j + 1]), fmaxf(s1[4 * j + 2], s1[4 * j + 3]));
  }
  float mx = fmaxf(fmaxf(fmaxf(a4[0], a4[1]), fmaxf(a4[2], a4[3])),
                   fmaxf(fmaxf(a4[4], a4[5]), fmaxf(a4[6], a4[7])));
  mx = xmax32(mx);
  // defer-max (T13): only rescale when some row's max grew by > 8 (log2 domain)
  if (!__all(mx <= m_ + 8.0f)) {
    float mn = fmaxf(m_, mx);
    float sc = exp2f(m_ - mn);
    m_ = mn;
    l_ *= sc;
#pragma unroll
    for (int r = 0; r < 16; ++r) { ctx0[r] *= sc; ctx1[r] *= sc; }
  }
#pragma unroll
  for (int r = 0; r < 16; ++r) s0[r] = exp2f(s0[r] - m_);
#pragma unroll
  for (int r = 0; r < 16; ++r) s1[r] = exp2f(s1[r] - m_);
  float b4[8];
#pragma unroll
  for (int j = 0; j < 4; ++j) {
    b4[j]     = (s0[4 * j] + s0[4 * j + 1]) + (s0[4 * j + 2] + s0[4 * j + 3]);
    b4[4 + j] = (s1[4 * j] + s1[4 * j + 1]) + (s1[4 * j + 2] + s1[4 * j + 3]);
  }
  float rs = ((b4[0] + b4[1]) + (b4[2] + b4[3])) + ((b4[4] + b4[5]) + (b4[6] + b4[7]));
  rs = xsum32(rs);
  l_ += rs;

  // pack P to bf16 dwords
  uint32_t pd0[8], pd1[8];
#pragma unroll
  for (int d = 0; d < 8; ++d) {
    pd0[d] = cvtpk(s0[2 * d], s0[2 * d + 1]);
    pd1[d] = cvtpk(s1[2 * d], s1[2 * d + 1]);
  }
  // PV: B-frag pairs via single permlane32_swap each
#pragma unroll
  for (int kvs = 0; kvs < 2; ++kvs) {
    const uint32_t* pd = kvs ? pd1 : pd0;
#pragma unroll
    for (int ks = 0; ks < 2; ++ks) {
      uint32_t u0 = pd[4 * ks], u2 = pd[4 * ks + 2];
      uint32_t u1 = pd[4 * ks + 1], u3 = pd[4 * ks + 3];
      plswap(u0, u2);
      plswap(u1, u3);
      union { uint32_t u[4]; short8 s; } bu;
      bu.u[0] = u0; bu.u[1] = u1; bu.u[2] = u2; bu.u[3] = u3;
      ctx0 = __builtin_amdgcn_mfma_f32_32x32x16_bf16(vf0[kvs * 2 + ks], bu.s, ctx0, 0, 0, 0);
      ctx1 = __builtin_amdgcn_mfma_f32_32x32x16_bf16(vf1[kvs * 2 + ks], bu.s, ctx1, 0, 0, 0);
    }
  }
}

__global__ __launch_bounds__(128) void k_attn(
    const unsigned short* __restrict__ Q, const unsigned short* __restrict__ KF,
    const unsigned short* __restrict__ VF, unsigned short* __restrict__ O) {
  __shared__ float lctx[64][33];
  __shared__ float lml[64][2];
  const int bid = blockIdx.x;              // 2048 blocks = 8 XCD * 4 head * 64 a
  const int xcd = bid & 7, idx = bid >> 3;
  const int head = idx >> 6;               // 4 heads per XCD -> K/V L2-resident
  const int a = idx & 63;
  const int qs = (head < 2) ? a : 63 - a;  // CU-level balance under RR placement
  const int bh = xcd * 4 + head;
  const int tid = threadIdx.x;
  const int wid = tid >> 6, lane = tid & 63;
  const int h = lane >> 5, c = lane & 31;
  const unsigned short* Qh = Q + (long)bh * 2048 * 64;
  const unsigned short* kfbase = KF + (long)bh * 131072 + lane * 8;
  const unsigned short* vfbase = VF + (long)bh * 131072 + lane * 8;
  const int q0 = qs * 32, qabs = q0 + c;
  const int nt = (qs >> 1) + 1, ntm1 = nt - 1;
  const int h0 = nt >> 1;                  // wave0: [0,h0) (can be empty), wave1: [h0,nt)
  const int Tbeg = wid ? h0 : 0;
  const int Tend = wid ? nt : h0;

  // Q fragment (B-operand): qf[dseg] = Q[q0+c][dseg*16+8h+j], roped in-lane.
  short8 qf[4];
  {
    const float lf = (float)(q0 + c);
#pragma unroll
    for (int d = 0; d < 4; ++d) {
      union { short8 s8; unsigned short s[8]; } u;
      u.s8 = *(const short8*)(Qh + (long)(q0 + c) * 64 + d * 16 + 8 * h);
#pragma unroll
      for (int jj = 0; jj < 4; ++jj) {
        int p = d * 8 + 4 * h + jj;      // rope pair index 0..31
        float ang = lf * exp2f(-(float)p * 0.4152410118609203f);  // log2(1e4)/32
        float sv, cv; sincosf(ang, &sv, &cv);
        float x1 = bf2f(u.s[2 * jj]), x2 = bf2f(u.s[2 * jj + 1]);
        u.s[2 * jj]     = f2bf((x1 * cv - x2 * sv) * 0.18033688011112042f);  // log2(e)/8
        u.s[2 * jj + 1] = f2bf((x1 * sv + x2 * cv) * 0.18033688011112042f);
      }
      qf[d] = u.s8;
    }
  }

  floatx16 ctx0 = {}, ctx1 = {};  // ctx^T[dv][q] partials
  float m_ = -1e30f, l_ = 0.f;

  if (Tbeg < Tend) {
    // prologue: K(Tbeg) into buffer A (coalesced)
    short8 kA0[4], kA1[4], kB0[4], kB1[4];
    const unsigned short* kt0 = kfbase + (long)Tbeg * 4096;
#pragma unroll
    for (int d = 0; d < 4; ++d) kA0[d] = *(const short8*)(kt0 + d * 512);
#pragma unroll
    for (int d = 0; d < 4; ++d) kA1[d] = *(const short8*)(kt0 + 2048 + d * 512);
    int T = Tbeg;
    while (true) {
      attn_tile(T, Tend, ntm1, qabs, h, c, kfbase, vfbase, qf, kA0, kA1, kB0, kB1, ctx0, ctx1, m_, l_);
      if (++T >= Tend) break;
      attn_tile(T, Tend, ntm1, qabs, h, c, kfbase, vfbase, qf, kB0, kB1, kA0, kA1, ctx0, ctx1, m_, l_);
      if (++T >= Tend) break;
    }
  }
  // combine the two waves' partials through LDS
  if (wid) {
#pragma unroll
    for (int r = 0; r < 16; ++r) {
      lctx[lane][r] = ctx0[r];
      lctx[lane][16 + r] = ctx1[r];
    }
    lml[lane][0] = m_;
    lml[lane][1] = l_;
  }
  __syncthreads();
  if (!wid) {
    float m1 = lml[lane][0], l1 = lml[lane][1];
    float m = fmaxf(m_, m1);
    float e0 = exp2f(m_ - m), e1 = exp2f(m1 - m);
    float inv = 1.f / (l_ * e0 + l1 * e1);
    const int b = bh >> 4, hd = bh & 15;
    unsigned short* orow = O + (long)(b * 2048 + q0 + c) * 1024 + hd * 64;
#pragma unroll
    for (int m4 = 0; m4 < 4; ++m4) {
      uint2 w0, w1;
      w0.x = cvtpk((ctx0[4 * m4]     * e0 + lctx[lane][4 * m4]     * e1) * inv,
                   (ctx0[4 * m4 + 1] * e0 + lctx[lane][4 * m4 + 1] * e1) * inv);
      w0.y = cvtpk((ctx0[4 * m4 + 2] * e0 + lctx[lane][4 * m4 + 2] * e1) * inv,
                   (ctx0[4 * m4 + 3] * e0 + lctx[lane][4 * m4 + 3] * e1) * inv);
      *(uint2*)(orow + 8 * m4 + 4 * h) = w0;
      w1.x = cvtpk((ctx1[4 * m4]     * e0 + lctx[lane][16 + 4 * m4]     * e1) * inv,
                   (ctx1[4 * m4 + 1] * e0 + lctx[lane][16 + 4 * m4 + 1] * e1) * inv);
      w1.y = cvtpk((ctx1[4 * m4 + 2] * e0 + lctx[lane][16 + 4 * m4 + 2] * e1) * inv,
                   (ctx1[4 * m4 + 3] * e0 + lctx[lane][16 + 4 * m4 + 3] * e1) * inv);
      *(uint2*)(orow + 32 + 8 * m4 + 4 * h) = w1;
    }
  }
}

extern "C" void kernel_launch(void* const* d_in, const int* in_sizes, int n_in,
                              void* d_out, int out_size, void* d_ws, size_t ws_size,
                              hipStream_t stream) {
  const float* X  = (const float*)d_in[0];
  const float* Wq = (const float*)d_in[1];
  const float* Wk = (const float*)d_in[2];
  const float* Wv = (const float*)d_in[3];
  const float* Wo = (const float*)d_in[4];
  unsigned short* Xb  = (unsigned short*)d_ws;   // [0,4M) bf16 X (dead after gemm0)
  unsigned short* Wqb = Xb + (4l << 20);
  unsigned short* Wkb = Xb + (5l << 20);
  unsigned short* Wvb = Xb + (6l << 20);
  unsigned short* Wob = Xb + (7l << 20);
  unsigned short* Qw  = Xb + (8l << 20);         // Q rows [2,16,2048,64] (un-roped)
  unsigned short* Kw  = Xb + (12l << 20);        // K rows (dead after ropeK)
  unsigned short* VFw = Xb + (16l << 20);        // fragment-major V (direct from gemm0)
  unsigned short* KFw = Xb;                      // fragment-major roped K (over dead X)
  unsigned short* Cw  = Xb + (20l << 20);        // ctx [b,l,1024]
  float* Out = (float*)d_out;

  k_convert<<<4096, 256, 0, stream>>>(X, Wq, Wk, Wv, Wo, Xb);
  k_gemm<0><<<dim3(32, 24), 256, 0, stream>>>(Xb, Wqb, Wkb, Wvb, Qw, Kw, VFw, nullptr, 1024);
  k_ropeK<<<1024, 256, 0, stream>>>(Kw, KFw);
  k_attn<<<2048, 128, 0, stream>>>(Qw, KFw, VFw, Cw);
  k_gemm<1><<<dim3(64, 8), 256, 0, stream>>>(Cw, Wob, nullptr, nullptr,
                                             nullptr, nullptr, nullptr, Out, 1024);
}

// Round 22
// 125.539 us; speedup vs baseline: 1.1157x; 1.0168x over previous
//
#include <hip/hip_runtime.h>
#include <stdint.h>

typedef __attribute__((ext_vector_type(8))) short short8;
typedef __attribute__((ext_vector_type(4))) float floatx4;
typedef __attribute__((ext_vector_type(16))) float floatx16;

#define DEV static __device__ __forceinline__

DEV unsigned short f2bf(float f) {
  union { float f; uint32_t u; } v; v.f = f;
  return (unsigned short)((v.u + 0x7FFFu + ((v.u >> 16) & 1u)) >> 16);
}
DEV float bf2f(unsigned short h) {
  union { uint32_t u; float f; } v; v.u = ((uint32_t)h) << 16;
  return v.f;
}
DEV uint32_t cvtpk(float lo, float hi) {
  uint32_t d;
  asm("v_cvt_pk_bf16_f32 %0, %1, %2" : "=v"(d) : "v"(lo), "v"(hi));
  return d;
}
DEV void gload_lds16(const void* g, void* l) {
  __builtin_amdgcn_global_load_lds(
      (const __attribute__((address_space(1))) uint32_t*)g,
      (__attribute__((address_space(3))) uint32_t*)l, 16, 0, 0);
}

// fast sincos: hardware v_sin/v_cos on revolutions; |err| ~2e-4 at |x|<=2048,
// far below bf16 storage error (4e-3). Used for RoPE only.
DEV void fsincos(float x, float* s, float* c) {
  const float r = x * 0.15915494309189535f;  // 1/(2*pi)
  *s = __sinf(x);  // lowers to v_sin_f32(fract path) via fast-math intrinsic
  *c = __cosf(x);
  (void)r;
}

#if defined(__has_builtin)
#if __has_builtin(__builtin_amdgcn_permlane32_swap)
#define HAVE_PLSWAP 1
#endif
#endif
DEV void plswap(uint32_t& a, uint32_t& b) {
#ifdef HAVE_PLSWAP
  typedef unsigned int u2v __attribute__((ext_vector_type(2)));
  u2v r = __builtin_amdgcn_permlane32_swap(a, b, false, false);
  a = r.x; b = r.y;
#else
  uint32_t sa = (uint32_t)__shfl_xor((int)a, 32);
  uint32_t sb = (uint32_t)__shfl_xor((int)b, 32);
  uint32_t lane = __lane_id();
  uint32_t na = lane < 32 ? a : sb;
  uint32_t nb = lane < 32 ? sa : b;
  a = na; b = nb;
#endif
}
DEV float xmax32(float x) {
  union { float f; uint32_t u; } a, b; a.f = x; b.f = x;
  plswap(a.u, b.u);
  return fmaxf(a.f, b.f);
}
DEV float xsum32(float x) {
  union { float f; uint32_t u; } a, b; a.f = x; b.f = x;
  plswap(a.u, b.u);
  return a.f + b.f;
}

// ---------- fp32 -> bf16 convert: [X 4M][wq 1M][wk 1M][wv 1M][wo 1M] ----------
__global__ __launch_bounds__(256) void k_convert(
    const float* __restrict__ X, const float* __restrict__ Wq,
    const float* __restrict__ Wk, const float* __restrict__ Wv,
    const float* __restrict__ Wo, unsigned short* __restrict__ out) {
  long gid = (long)blockIdx.x * 256 + threadIdx.x;
  long e = gid * 8;
  int seg = (int)(e >> 20);
  const float* src; long base;
  if (seg < 4)      { src = X;  base = 0; }
  else if (seg == 4){ src = Wq; base = 4l << 20; }
  else if (seg == 5){ src = Wk; base = 5l << 20; }
  else if (seg == 6){ src = Wv; base = 6l << 20; }
  else              { src = Wo; base = 7l << 20; }
  const float4* s4 = (const float4*)(src + (e - base));
  float4 a = s4[0], b = s4[1];
  union { uint4 q; unsigned short s[8]; } u;
  u.s[0] = f2bf(a.x); u.s[1] = f2bf(a.y); u.s[2] = f2bf(a.z); u.s[3] = f2bf(a.w);
  u.s[4] = f2bf(b.x); u.s[5] = f2bf(b.y); u.s[6] = f2bf(b.z); u.s[7] = f2bf(b.w);
  *(uint4*)(out + e) = u.q;
}

// ---------- GEMM C = A * W^T   (A: MxK bf16 rm, W: NxK bf16 rm) ----------
// T2 swizzle per rule #21; K-loop start staggered per block.
// MODE 0: 128x128 tile; QKV fused epilogue. MODE 1: 64x128 tile, f32 out.
template <int MODE>
__global__ __launch_bounds__(256) void k_gemm(
    const unsigned short* __restrict__ A,
    const unsigned short* __restrict__ B0, const unsigned short* __restrict__ B1,
    const unsigned short* __restrict__ B2,
    unsigned short* __restrict__ Qo, unsigned short* __restrict__ Ko,
    unsigned short* __restrict__ VFo, float* __restrict__ Cf, int K) {
  constexpr int MI = (MODE == 1) ? 2 : 4;   // acc rows per wave (of 16)
  constexpr int BM = MI * 32;               // 64 or 128
  __shared__ unsigned short At[BM * 64];
  __shared__ unsigned short Bt[128 * 64];
  const int tid = threadIdx.x, lane = tid & 63, wid = tid >> 6;
  const int wm = (wid >> 1) * (MI * 16), wn = (wid & 1) * 64;
  const int g = lane >> 4, c0 = lane & 15;
  const int bm0 = blockIdx.x * BM;
  const int bnG = blockIdx.y * 128;
  const unsigned short* Bp;
  int bn0;
  if constexpr (MODE == 0) {
    int wsel = bnG >> 10;
    Bp = wsel == 0 ? B0 : (wsel == 1 ? B1 : B2);
    bn0 = bnG & 1023;
  } else { Bp = B0; bn0 = bnG; }
  floatx4 acc[MI][4] = {};
  const int nk = K >> 6;
  const int koff = (blockIdx.x + blockIdx.y * 3) & (nk - 1);
  const int swzr = (c0 & 7) << 4;
  for (int s = 0; s < nk; ++s) {
    const int kt = ((s + koff) & (nk - 1)) << 6;
#pragma unroll
    for (int i = 0; i < MI; ++i) {
      int o = tid * 16 + i * 4096;
      int row = o >> 7;
      int col = (o & 127) ^ ((row & 7) << 4);
      gload_lds16((const char*)A + ((long)(bm0 + row) * K + kt + (col >> 1)) * 2, (char*)At + o);
    }
#pragma unroll
    for (int i = 0; i < 4; ++i) {
      int o = tid * 16 + i * 4096;
      int row = o >> 7;
      int col = (o & 127) ^ ((row & 7) << 4);
      gload_lds16((const char*)Bp + ((long)(bn0 + row) * K + kt + (col >> 1)) * 2, (char*)Bt + o);
    }
    __syncthreads();
#pragma unroll
    for (int kk = 0; kk < 2; ++kk) {
      const int kb = kk * 64 + g * 16;
      short8 av[MI], bv[4];
#pragma unroll
      for (int mi = 0; mi < MI; ++mi)
        av[mi] = *(const short8*)((const char*)At + (wm + mi * 16 + c0) * 128 + (kb ^ swzr));
#pragma unroll
      for (int ni = 0; ni < 4; ++ni)
        bv[ni] = *(const short8*)((const char*)Bt + (wn + ni * 16 + c0) * 128 + (kb ^ swzr));
#pragma unroll
      for (int mi = 0; mi < MI; ++mi)
#pragma unroll
        for (int ni = 0; ni < 4; ++ni)
          acc[mi][ni] = __builtin_amdgcn_mfma_f32_16x16x32_bf16(av[mi], bv[ni], acc[mi][ni], 0, 0, 0);
    }
    __syncthreads();
  }
  if constexpr (MODE == 1) {
#pragma unroll
    for (int mi = 0; mi < MI; ++mi)
#pragma unroll
      for (int ni = 0; ni < 4; ++ni)
#pragma unroll
        for (int i = 0; i < 4; ++i) {
          int r = bm0 + wm + mi * 16 + 4 * g + i;
          int cg = bnG + wn + ni * 16 + c0;
          Cf[(long)r * 1024 + cg] = acc[mi][ni][i];
        }
  } else {
    const int wsel = bnG >> 10;  // block-uniform: 0=Q, 1=K, 2=V
#pragma unroll
    for (int mi = 0; mi < MI; ++mi)
#pragma unroll
      for (int ni = 0; ni < 4; ++ni)
#pragma unroll
        for (int i = 0; i < 4; ++i) {
          int r = bm0 + wm + mi * 16 + 4 * g + i;
          int cg = bnG + wn + ni * 16 + c0;
          int cc = cg & 1023, head = cc >> 6, dkk = cc & 63;
          int bb = r >> 11, ll = r & 2047;
          long bh = bb * 16 + head;
          float v = acc[mi][ni][i];
          if (wsel == 2) {
            int T = ll >> 6, rt = ll & 63;
            int m = rt >> 4, hb = (rt >> 3) & 1, j = rt & 7;
            int dvs = dkk >> 5, c = dkk & 31;
            VFo[bh * 131072 + T * 4096 + (dvs * 4 + m) * 512 + (hb * 32 + c) * 8 + j] = f2bf(v);
          } else {
            unsigned short* dst = wsel == 0 ? Qo : Ko;
            dst[(bh * 2048 + ll) * 64 + dkk] = f2bf(v);
          }
        }
  }
}

// ---------- K: rope + repack to fragment-major KF[bh][T][kvs][dseg][lane][8] ----------
__global__ __launch_bounds__(256) void k_ropeK(
    const unsigned short* __restrict__ Kin, unsigned short* __restrict__ KF) {
  const int kblk = blockIdx.x;           // 1024 = 32bh * 32T
  const int bh = kblk >> 5, T = kblk & 31;
  const int tid = threadIdx.x;
  const unsigned short* src = Kin + ((long)bh * 2048 + T * 64) * 64;
  unsigned short* dst = KF + (long)kblk * 4096;
#pragma unroll
  for (int it = 0; it < 2; ++it) {
    int u = tid + it * 256;              // (kvs*4+dseg)*64 + lane
    int lane = u & 63, kd = u >> 6;
    int kvs = kd >> 2, dseg = kd & 3;
    int row = kvs * 32 + (lane & 31);
    int col = dseg * 16 + 8 * (lane >> 5);
    union { uint4 q; unsigned short s[8]; } v;
    v.q = *(const uint4*)(src + row * 64 + col);
    float lf = (float)(T * 64 + row);
#pragma unroll
    for (int j = 0; j < 4; ++j) {
      int p = (col >> 1) + j;            // rope pair index 0..31
      float ang = lf * exp2f(-(float)p * 0.4152410118609203f);
      float sv, cv;
      fsincos(ang, &sv, &cv);
      float x1 = bf2f(v.s[2 * j]), x2 = bf2f(v.s[2 * j + 1]);
      v.s[2 * j]     = f2bf(x1 * cv - x2 * sv);
      v.s[2 * j + 1] = f2bf(x1 * sv + x2 * cv);
    }
    *(uint4*)(dst + u * 8) = v.q;
  }
}

// ---------- causal flash attention: 32x32 swapped MFMA, 2-way KV-split ----------
// 2 waves/block, same 32 q-rows; wave0 KV tiles [0,h0), wave1 [h0,nt).
// Lane (h=lane>>5, c=lane&31) owns q-row q0+c; KF/VF loads lane-contiguous.
// Q-rope folded into the fragment load (pairs adjacent in-lane; fast trig).
DEV void attn_tile(int T, int Tend, int ntm1, int qabs, int h, int c,
                   const unsigned short* __restrict__ kfbase,
                   const unsigned short* __restrict__ vfbase,
                   const short8 (&qf)[4],
                   const short8 (&kc0)[4], const short8 (&kc1)[4],
                   short8 (&kn0)[4], short8 (&kn1)[4],
                   floatx16& ctx0, floatx16& ctx1, float& m_, float& l_) {
  // prefetch K(T+1) into the other buffer (coalesced 1KB bursts)
  {
    const int Tn = T + 1 < Tend ? T + 1 : T;
    const unsigned short* kt = kfbase + (long)Tn * 4096;
#pragma unroll
    for (int d = 0; d < 4; ++d) kn0[d] = *(const short8*)(kt + d * 512);
#pragma unroll
    for (int d = 0; d < 4; ++d) kn1[d] = *(const short8*)(kt + 2048 + d * 512);
  }
  // V fragments for this tile (coalesced; consumed after softmax)
  const unsigned short* vt = vfbase + (long)T * 4096;
  short8 vf0[4], vf1[4];
#pragma unroll
  for (int m = 0; m < 4; ++m) vf0[m] = *(const short8*)(vt + m * 512);
#pragma unroll
  for (int m = 0; m < 4; ++m) vf1[m] = *(const short8*)(vt + 2048 + m * 512);

  // S^T tiles from current (already-resident) K fragments
  floatx16 s0 = {}, s1 = {};
#pragma unroll
  for (int d = 0; d < 4; ++d)
    s0 = __builtin_amdgcn_mfma_f32_32x32x16_bf16(kc0[d], qf[d], s0, 0, 0, 0);
#pragma unroll
  for (int d = 0; d < 4; ++d)
    s1 = __builtin_amdgcn_mfma_f32_32x32x16_bf16(kc1[d], qf[d], s1, 0, 0, 0);

  // causal mask (uniform branch, final tile of the q-block only)
  if (T == ntm1) {
    const int kvb = T * 64 + 4 * h;
#pragma unroll
    for (int r = 0; r < 16; ++r) {
      const int off = (r & 3) + 8 * (r >> 2);
      if (kvb + off > qabs) s0[r] = -1e30f;
      if (kvb + 32 + off > qabs) s1[r] = -1e30f;
    }
  }
  // softmax: depth-5 in-lane trees + permlane cross-half
  float a4[8];
#pragma unroll
  for (int j = 0; j < 4; ++j) {
    a4[j]     = fmaxf(fmaxf(s0[4 * j], s0[4 * j + 1]), fmaxf(s0[4 * j + 2], s0[4 * j + 3]));
    a4[4 + j] = fmaxf(fmaxf(s1[4 * j], s1[4 * j + 1]), fmaxf(s1[4 * j + 2], s1[4 * j + 3]));
  }
  float mx = fmaxf(fmaxf(fmaxf(a4[0], a4[1]), fmaxf(a4[2], a4[3])),
                   fmaxf(fmaxf(a4[4], a4[5]), fmaxf(a4[6], a4[7])));
  mx = xmax32(mx);
  // defer-max (T13): only rescale when some row's max grew by > 8 (log2 domain)
  if (!__all(mx <= m_ + 8.0f)) {
    float mn = fmaxf(m_, mx);
    float sc = exp2f(m_ - mn);
    m_ = mn;
    l_ *= sc;
#pragma unroll
    for (int r = 0; r < 16; ++r) { ctx0[r] *= sc; ctx1[r] *= sc; }
  }
#pragma unroll
  for (int r = 0; r < 16; ++r) s0[r] = exp2f(s0[r] - m_);
#pragma unroll
  for (int r = 0; r < 16; ++r) s1[r] = exp2f(s1[r] - m_);
  float b4[8];
#pragma unroll
  for (int j = 0; j < 4; ++j) {
    b4[j]     = (s0[4 * j] + s0[4 * j + 1]) + (s0[4 * j + 2] + s0[4 * j + 3]);
    b4[4 + j] = (s1[4 * j] + s1[4 * j + 1]) + (s1[4 * j + 2] + s1[4 * j + 3]);
  }
  float rs = ((b4[0] + b4[1]) + (b4[2] + b4[3])) + ((b4[4] + b4[5]) + (b4[6] + b4[7]));
  rs = xsum32(rs);
  l_ += rs;

  // pack P to bf16 dwords
  uint32_t pd0[8], pd1[8];
#pragma unroll
  for (int d = 0; d < 8; ++d) {
    pd0[d] = cvtpk(s0[2 * d], s0[2 * d + 1]);
    pd1[d] = cvtpk(s1[2 * d], s1[2 * d + 1]);
  }
  // PV: B-frag pairs via single permlane32_swap each
#pragma unroll
  for (int kvs = 0; kvs < 2; ++kvs) {
    const uint32_t* pd = kvs ? pd1 : pd0;
#pragma unroll
    for (int ks = 0; ks < 2; ++ks) {
      uint32_t u0 = pd[4 * ks], u2 = pd[4 * ks + 2];
      uint32_t u1 = pd[4 * ks + 1], u3 = pd[4 * ks + 3];
      plswap(u0, u2);
      plswap(u1, u3);
      union { uint32_t u[4]; short8 s; } bu;
      bu.u[0] = u0; bu.u[1] = u1; bu.u[2] = u2; bu.u[3] = u3;
      ctx0 = __builtin_amdgcn_mfma_f32_32x32x16_bf16(vf0[kvs * 2 + ks], bu.s, ctx0, 0, 0, 0);
      ctx1 = __builtin_amdgcn_mfma_f32_32x32x16_bf16(vf1[kvs * 2 + ks], bu.s, ctx1, 0, 0, 0);
    }
  }
}

__global__ __launch_bounds__(128) void k_attn(
    const unsigned short* __restrict__ Q, const unsigned short* __restrict__ KF,
    const unsigned short* __restrict__ VF, unsigned short* __restrict__ O) {
  __shared__ float lctx[64][33];
  __shared__ float lml[64][2];
  const int bid = blockIdx.x;              // 2048 blocks = 8 XCD * 4 head * 64 a
  const int xcd = bid & 7, idx = bid >> 3;
  const int head = idx >> 6;               // 4 heads per XCD -> K/V L2-resident
  const int a = idx & 63;
  const int qs = (head < 2) ? a : 63 - a;  // CU-level balance under RR placement
  const int bh = xcd * 4 + head;
  const int tid = threadIdx.x;
  const int wid = tid >> 6, lane = tid & 63;
  const int h = lane >> 5, c = lane & 31;
  const unsigned short* Qh = Q + (long)bh * 2048 * 64;
  const unsigned short* kfbase = KF + (long)bh * 131072 + lane * 8;
  const unsigned short* vfbase = VF + (long)bh * 131072 + lane * 8;
  const int q0 = qs * 32, qabs = q0 + c;
  const int nt = (qs >> 1) + 1, ntm1 = nt - 1;
  const int h0 = nt >> 1;                  // wave0: [0,h0) (can be empty), wave1: [h0,nt)
  const int Tbeg = wid ? h0 : 0;
  const int Tend = wid ? nt : h0;

  // Q fragment (B-operand): qf[dseg] = Q[q0+c][dseg*16+8h+j], roped in-lane.
  short8 qf[4];
  {
    const float lf = (float)(q0 + c);
#pragma unroll
    for (int d = 0; d < 4; ++d) {
      union { short8 s8; unsigned short s[8]; } u;
      u.s8 = *(const short8*)(Qh + (long)(q0 + c) * 64 + d * 16 + 8 * h);
#pragma unroll
      for (int jj = 0; jj < 4; ++jj) {
        int p = d * 8 + 4 * h + jj;      // rope pair index 0..31
        float ang = lf * exp2f(-(float)p * 0.4152410118609203f);  // log2(1e4)/32
        float sv, cv;
        fsincos(ang, &sv, &cv);
        float x1 = bf2f(u.s[2 * jj]), x2 = bf2f(u.s[2 * jj + 1]);
        u.s[2 * jj]     = f2bf((x1 * cv - x2 * sv) * 0.18033688011112042f);  // log2(e)/8
        u.s[2 * jj + 1] = f2bf((x1 * sv + x2 * cv) * 0.18033688011112042f);
      }
      qf[d] = u.s8;
    }
  }

  floatx16 ctx0 = {}, ctx1 = {};  // ctx^T[dv][q] partials
  float m_ = -1e30f, l_ = 0.f;

  if (Tbeg < Tend) {
    // prologue: K(Tbeg) into buffer A (coalesced)
    short8 kA0[4], kA1[4], kB0[4], kB1[4];
    const unsigned short* kt0 = kfbase + (long)Tbeg * 4096;
#pragma unroll
    for (int d = 0; d < 4; ++d) kA0[d] = *(const short8*)(kt0 + d * 512);
#pragma unroll
    for (int d = 0; d < 4; ++d) kA1[d] = *(const short8*)(kt0 + 2048 + d * 512);
    int T = Tbeg;
    while (true) {
      attn_tile(T, Tend, ntm1, qabs, h, c, kfbase, vfbase, qf, kA0, kA1, kB0, kB1, ctx0, ctx1, m_, l_);
      if (++T >= Tend) break;
      attn_tile(T, Tend, ntm1, qabs, h, c, kfbase, vfbase, qf, kB0, kB1, kA0, kA1, ctx0, ctx1, m_, l_);
      if (++T >= Tend) break;
    }
  }
  // combine the two waves' partials through LDS
  if (wid) {
#pragma unroll
    for (int r = 0; r < 16; ++r) {
      lctx[lane][r] = ctx0[r];
      lctx[lane][16 + r] = ctx1[r];
    }
    lml[lane][0] = m_;
    lml[lane][1] = l_;
  }
  __syncthreads();
  if (!wid) {
    float m1 = lml[lane][0], l1 = lml[lane][1];
    float m = fmaxf(m_, m1);
    float e0 = exp2f(m_ - m), e1 = exp2f(m1 - m);
    float inv = 1.f / (l_ * e0 + l1 * e1);
    const int b = bh >> 4, hd = bh & 15;
    unsigned short* orow = O + (long)(b * 2048 + q0 + c) * 1024 + hd * 64;
#pragma unroll
    for (int m4 = 0; m4 < 4; ++m4) {
      uint2 w0, w1;
      w0.x = cvtpk((ctx0[4 * m4]     * e0 + lctx[lane][4 * m4]     * e1) * inv,
                   (ctx0[4 * m4 + 1] * e0 + lctx[lane][4 * m4 + 1] * e1) * inv);
      w0.y = cvtpk((ctx0[4 * m4 + 2] * e0 + lctx[lane][4 * m4 + 2] * e1) * inv,
                   (ctx0[4 * m4 + 3] * e0 + lctx[lane][4 * m4 + 3] * e1) * inv);
      *(uint2*)(orow + 8 * m4 + 4 * h) = w0;
      w1.x = cvtpk((ctx1[4 * m4]     * e0 + lctx[lane][16 + 4 * m4]     * e1) * inv,
                   (ctx1[4 * m4 + 1] * e0 + lctx[lane][16 + 4 * m4 + 1] * e1) * inv);
      w1.y = cvtpk((ctx1[4 * m4 + 2] * e0 + lctx[lane][16 + 4 * m4 + 2] * e1) * inv,
                   (ctx1[4 * m4 + 3] * e0 + lctx[lane][16 + 4 * m4 + 3] * e1) * inv);
      *(uint2*)(orow + 32 + 8 * m4 + 4 * h) = w1;
    }
  }
}

extern "C" void kernel_launch(void* const* d_in, const int* in_sizes, int n_in,
                              void* d_out, int out_size, void* d_ws, size_t ws_size,
                              hipStream_t stream) {
  const float* X  = (const float*)d_in[0];
  const float* Wq = (const float*)d_in[1];
  const float* Wk = (const float*)d_in[2];
  const float* Wv = (const float*)d_in[3];
  const float* Wo = (const float*)d_in[4];
  unsigned short* Xb  = (unsigned short*)d_ws;   // [0,4M) bf16 X (dead after gemm0)
  unsigned short* Wqb = Xb + (4l << 20);
  unsigned short* Wkb = Xb + (5l << 20);
  unsigned short* Wvb = Xb + (6l << 20);
  unsigned short* Wob = Xb + (7l << 20);
  unsigned short* Qw  = Xb + (8l << 20);         // Q rows [2,16,2048,64] (un-roped)
  unsigned short* Kw  = Xb + (12l << 20);        // K rows (dead after ropeK)
  unsigned short* VFw = Xb + (16l << 20);        // fragment-major V (direct from gemm0)
  unsigned short* KFw = Xb;                      // fragment-major roped K (over dead X)
  unsigned short* Cw  = Xb + (20l << 20);        // ctx [b,l,1024]
  float* Out = (float*)d_out;

  k_convert<<<4096, 256, 0, stream>>>(X, Wq, Wk, Wv, Wo, Xb);
  k_gemm<0><<<dim3(32, 24), 256, 0, stream>>>(Xb, Wqb, Wkb, Wvb, Qw, Kw, VFw, nullptr, 1024);
  k_ropeK<<<1024, 256, 0, stream>>>(Kw, KFw);
  k_attn<<<2048, 128, 0, stream>>>(Qw, KFw, VFw, Cw);
  k_gemm<1><<<dim3(64, 8), 256, 0, stream>>>(Cw, Wob, nullptr, nullptr,
                                             nullptr, nullptr, nullptr, Out, 1024);
}